// Round 14
// baseline (150.232 us; speedup 1.0000x reference)
//
#include <hip/hip_runtime.h>
#include <hip/hip_bf16.h>
#include <cstddef>

// Problem constants
#define B_ROWS 16384
#define SDIM 512
#define ADIM 64
#define KDIM 576    // SDIM + ADIM = 9 K-tiles of 64 (exact)
#define HID 1024
#define NQ 64

// prep: transposes + qoff only
#define T1_BLOCKS ((KDIM / 32) * (HID / 32))   // 576
#define T2_BLOCKS ((HID / 32) * (HID / 32))    // 1024
#define PREP_BLOCKS (T1_BLOCKS + T2_BLOCKS + 1)

#define FK_LDS 65536   // 8 A-buffers x 8KB

typedef __attribute__((ext_vector_type(8))) __bf16 bf16x8;
typedef __attribute__((ext_vector_type(4))) float f32x4;

static __device__ __forceinline__ float bf2f(unsigned short u) {
  union { unsigned int i; float f; } x; x.i = ((unsigned int)u) << 16; return x.f;
}
static __device__ __forceinline__ unsigned short f2bf(float f) {
  union { float f; unsigned int i; } x; x.f = f;
  unsigned int i = x.i + (0x7fffu + ((x.i >> 16) & 1u)); // RNE
  return (unsigned short)(i >> 16);
}

static __device__ __forceinline__ void gload_lds16(const unsigned short* g, unsigned short* l) {
  __builtin_amdgcn_global_load_lds(
      (const __attribute__((address_space(1))) void*)(const void*)g,
      (__attribute__((address_space(3))) void*)(void*)l, 16, 0, 0);
}

// pack 8 f32 -> 8 bf16 (RNE) in one uint4
static __device__ __forceinline__ uint4 pack8(float4 a, float4 b) {
  uint4 o;
  o.x = (unsigned)f2bf(a.x) | ((unsigned)f2bf(a.y) << 16);
  o.y = (unsigned)f2bf(a.z) | ((unsigned)f2bf(a.w) << 16);
  o.z = (unsigned)f2bf(b.x) | ((unsigned)f2bf(b.y) << 16);
  o.w = (unsigned)f2bf(b.z) | ((unsigned)f2bf(b.w) << 16);
  return o;
}

// ---- transpose helper: W [Kin][N] f32 -> Wb [N][Kin] bf16 ----
static __device__ __forceinline__ void transpose_body(
    const float* __restrict__ W, unsigned short* __restrict__ Wb,
    int Kin, int N, int k0, int n0, unsigned short* tile) {
  const int tx = threadIdx.x & 31, ty = threadIdx.x >> 5;
#pragma unroll
  for (int i = 0; i < 32; i += 8)
    tile[(ty + i) * 33 + tx] = f2bf(W[(size_t)(k0 + ty + i) * N + n0 + tx]);
  __syncthreads();
#pragma unroll
  for (int i = 0; i < 32; i += 8)
    Wb[(size_t)(n0 + ty + i) * Kin + k0 + tx] = tile[tx * 33 + ty + i];
}

// ---- prep: weight transposes + qoff ----
__global__ __launch_bounds__(256) void prep_k(
    const float* __restrict__ W1, const float* __restrict__ W2,
    const float* __restrict__ Wq1, const float* __restrict__ bq1,
    const float* __restrict__ Wq2, const float* __restrict__ bq2,
    const float* __restrict__ Wh, const float* __restrict__ bh,
    unsigned short* __restrict__ w1b, unsigned short* __restrict__ w2b,
    float* __restrict__ qoff) {
  __shared__ unsigned short tile[32 * 33];
  const int b = blockIdx.x;
  if (b < T1_BLOCKS) {
    transpose_body(W1, w1b, KDIM, HID, (b / 32) * 32, (b % 32) * 32, tile);
  } else if (b < T1_BLOCKS + T2_BLOCKS) {
    const int t = b - T1_BLOCKS;
    transpose_body(W2, w2b, HID, HID, (t / 32) * 32, (t % 32) * 32, tile);
  } else {
    const int q = threadIdx.x;
    if (q < NQ) {
      const float tau = ((float)q + 0.5f) * (1.0f / (float)NQ);
      float t1[64];
#pragma unroll
      for (int k = 0; k < 64; ++k) t1[k] = fmaxf(fmaf(tau, Wq1[k], bq1[k]), 0.f);
      float acc = bh[0];
#pragma unroll 1
      for (int j = 0; j < 64; ++j) {
        float t2 = bq2[j];
#pragma unroll
        for (int k = 0; k < 64; ++k) t2 = fmaf(t1[k], Wq2[k * 64 + j], t2);
        acc = fmaf(t2, Wh[HID + j], acc);
      }
      qoff[q] = acc;
    }
  }
}

// ============================================================================
// Row-stripe fused GEMM+LN, round-14 structure:
//  - B fragments loaded DIRECT global->register in MFMA layout (B has zero
//    block-level reuse; bypassing LDS removes 128KB/tile of LDS port traffic
//    and all B-related barrier coupling). Prefetch b0/b1 one tile ahead with
//    compiler-counted vmcnt waits.
//  - A (8KB/tile) in LDS, 8 buffers (64KB), staged 4 tiles ahead into the
//    opposite 4-buffer half; s_barrier only every 4 tiles -> waves drift and
//    cover each other's latency. WAITVM(16) at group barrier drains A-stages
//    (leaves the 16 in-flight B loads).
//  - NT is a template arg (9/16): fully unrolled straight-line body.
// Epilogue (r11-r13 verified): cross-wave LDS tree-reduce row mean/var,
// LN+ReLU on f32 accs; FINAL adds rank-1 Wf-dot + qoff -> f32 out.
// ============================================================================
template <bool XSRC, bool FINAL, int NT>
__global__ __launch_bounds__(512) void fused_k(
    const float* __restrict__ Xs,           // state  [M][512]   (XSRC)
    const float* __restrict__ Xa,           // action [M][64]    (XSRC)
    const unsigned short* __restrict__ A,   // [M][K] bf16       (!XSRC)
    const unsigned short* __restrict__ Bt,  // [1024][K] bf16 (W transposed)
    const float* __restrict__ bias, const float* __restrict__ g,
    const float* __restrict__ be, const float* __restrict__ Wh,
    const float* __restrict__ qoff,
    unsigned short* __restrict__ Hout, float* __restrict__ Qout,
    int K) {
  extern __shared__ unsigned short sm[];    // 8 x 8KB A buffers
  __shared__ float part[8][64][2];
  __shared__ float murs[64][2];
  __shared__ float dotf[64];
  __shared__ float qof[64];

  const int tid = threadIdx.x;
  const int w = tid >> 6, l = tid & 63;
  const int r0 = (int)blockIdx.x * 64;
  const int sb = (int)blockIdx.x % NT;      // K-order stagger

  const int sce = ((((l & 7) << 4) ^ (((l >> 3) & 4) << 3)) >> 1);
  const int lr = (l & 15) << 7;
  const int cSw = (((l >> 4) << 4) ^ ((l & 4) << 3));

  f32x4 acc[4][8] = {};
  bf16x8 b0[8], b1[8];
  float4 ar0, ar1, br0, br1;                // XSRC staging regs

  // per-lane B row pointer: row = w*128 + (l&15), col base (l>>4)*8
  const unsigned short* Bp = Bt + (size_t)(w * 128 + (l & 15)) * K + ((l >> 4) << 3);

#define KT(x) ((((x) + sb) % NT) << 6)
#define AF(d, mi, kk) (*(const bf16x8*)(sm + (((d)*8192 + (mi)*2048 + lr + cSw + ((kk) << 6)) >> 1)))
#define ISSUE_A(d, kt) \
    gload_lds16(A + (size_t)(r0 + w * 8 + (l >> 3)) * K + (kt) + sce, \
                sm + (((d)*8192 + w * 1024) >> 1))
#define ALOADX(q0, q1, kt) do { \
    const int row_ = r0 + w * 8 + (l >> 3); \
    if ((kt) < SDIM) { const float* p_ = Xs + (size_t)row_ * SDIM + (kt) + sce; \
      q0 = *(const float4*)p_; q1 = *(const float4*)(p_ + 4); } \
    else { const float* p_ = Xa + (size_t)row_ * ADIM + ((kt) - SDIM) + sce; \
      q0 = *(const float4*)p_; q1 = *(const float4*)(p_ + 4); } } while (0)
#define AWRX(d, q0, q1) (*(uint4*)(sm + (((d)*8192 + w * 1024 + l * 16) >> 1)) = pack8(q0, q1))
#define LOADB(dst, kt, kk) do { _Pragma("unroll") for (int ni = 0; ni < 8; ++ni) \
    dst[ni] = *(const bf16x8*)(Bp + (size_t)(ni * 16) * K + (kt) + (kk) * 32); } while (0)
#define BAR() __builtin_amdgcn_s_barrier()
#define WAITLGKM() asm volatile("s_waitcnt lgkmcnt(0)" ::: "memory")
#define WAITVM16() asm volatile("s_waitcnt vmcnt(16)" ::: "memory")

  // ---------------- prologue: A(0..3) into buffers 0-3, B(0) in flight ----
  if (XSRC) {
    ALOADX(ar0, ar1, KT(0)); ALOADX(br0, br1, KT(1));
    AWRX(0, ar0, ar1);
    ALOADX(ar0, ar1, KT(2));
    AWRX(1, br0, br1);
    ALOADX(br0, br1, KT(3));
    AWRX(2, ar0, ar1);
    AWRX(3, br0, br1);
    LOADB(b0, KT(0), 0); LOADB(b1, KT(0), 1);
    WAITLGKM(); BAR();
  } else {
    ISSUE_A(0, KT(0)); ISSUE_A(1, KT(1)); ISSUE_A(2, KT(2)); ISSUE_A(3, KT(3));
    LOADB(b0, KT(0), 0); LOADB(b1, KT(0), 1);
    WAITVM16(); BAR();
  }

  // ---------------- main loop: fully unrolled ----------------
#pragma unroll
  for (int t = 0; t < NT; ++t) {
    const int d = t & 7;
    bf16x8 af[4];
    // A stage for tile t+4 (opposite buffer half), issued before b0(t+1)
    if (XSRC) {
      if (t + 4 < NT) ALOADX(ar0, ar1, KT(t + 4));
    } else {
      if (t + 4 < NT) ISSUE_A((t + 4) & 7, KT(t + 4));
    }
    // kk = 0
#pragma unroll
    for (int mi = 0; mi < 4; ++mi) af[mi] = AF(d, mi, 0);
    __builtin_amdgcn_s_setprio(1);
#pragma unroll
    for (int mi = 0; mi < 4; ++mi)
#pragma unroll
      for (int ni = 0; ni < 8; ++ni)
        acc[mi][ni] = __builtin_amdgcn_mfma_f32_16x16x32_bf16(af[mi], b0[ni], acc[mi][ni], 0, 0, 0);
    __builtin_amdgcn_s_setprio(0);
    if (t + 1 < NT) LOADB(b0, KT(t + 1), 0);   // b0 regs free, prefetch
    // kk = 1
#pragma unroll
    for (int mi = 0; mi < 4; ++mi) af[mi] = AF(d, mi, 1);
    __builtin_amdgcn_s_setprio(1);
#pragma unroll
    for (int mi = 0; mi < 4; ++mi)
#pragma unroll
      for (int ni = 0; ni < 8; ++ni)
        acc[mi][ni] = __builtin_amdgcn_mfma_f32_16x16x32_bf16(af[mi], b1[ni], acc[mi][ni], 0, 0, 0);
    __builtin_amdgcn_s_setprio(0);
    if (t + 1 < NT) LOADB(b1, KT(t + 1), 1);
    // XSRC: convert + ds_write A(t+4) (pack8 auto-waits the f32 loads,
    // which are older than b0/b1(t+1) -> B prefetch stays in flight)
    if (XSRC && t + 4 < NT) AWRX((t + 4) & 7, ar0, ar1);
    // group barrier every 4 tiles (publishes next half's A)
    if (((t & 3) == 3) && (t + 1 < NT)) {
      if (XSRC) { WAITLGKM(); } 
      WAITVM16();
      BAR();
    }
  }

  // ---------------- epilogue (r11-r13 verified) ----------------
  __syncthreads();
  float bcol[8], gcol[8], becol[8];
#pragma unroll
  for (int ni = 0; ni < 8; ++ni) {
    const int col = w * 128 + ni * 16 + (l & 15);
    bcol[ni] = bias[col];
    gcol[ni] = g[col];
    becol[ni] = be[col];
  }
#pragma unroll
  for (int mi = 0; mi < 4; ++mi)
#pragma unroll
    for (int rr = 0; rr < 4; ++rr) {
      float s1 = 0.f, s2 = 0.f;
#pragma unroll
      for (int ni = 0; ni < 8; ++ni) {
        const float x = acc[mi][ni][rr] + bcol[ni];
        s1 += x; s2 += x * x;
      }
#pragma unroll
      for (int o = 1; o < 16; o <<= 1) {
        s1 += __shfl_xor(s1, o, 64);
        s2 += __shfl_xor(s2, o, 64);
      }
      if ((l & 15) == 0) {
        const int row = mi * 16 + (l >> 4) * 4 + rr;
        part[w][row][0] = s1;
        part[w][row][1] = s2;
      }
    }
  __syncthreads();
  if (tid < 64) {
    float s1 = 0.f, s2 = 0.f;
#pragma unroll
    for (int ww = 0; ww < 8; ++ww) { s1 += part[ww][tid][0]; s2 += part[ww][tid][1]; }
    const float mu = s1 * (1.0f / HID);
    murs[tid][0] = mu;
    murs[tid][1] = rsqrtf(s2 * (1.0f / HID) - mu * mu + 1e-5f);
    if (FINAL) qof[tid] = qoff[tid];
  }
  __syncthreads();

  if (!FINAL) {
#pragma unroll
    for (int mi = 0; mi < 4; ++mi)
#pragma unroll
      for (int rr = 0; rr < 4; ++rr) {
        const int row = mi * 16 + (l >> 4) * 4 + rr;
        const float mu = murs[row][0], rs = murs[row][1];
        unsigned short* hp = Hout + (size_t)(r0 + row) * HID + w * 128 + (l & 15);
#pragma unroll
        for (int ni = 0; ni < 8; ++ni) {
          const float x = acc[mi][ni][rr] + bcol[ni];
          hp[ni * 16] = f2bf(fmaxf((x - mu) * rs * gcol[ni] + becol[ni], 0.f));
        }
      }
  } else {
    float wf[8];
#pragma unroll
    for (int ni = 0; ni < 8; ++ni) wf[ni] = Wh[w * 128 + ni * 16 + (l & 15)];
#pragma unroll
    for (int mi = 0; mi < 4; ++mi)
#pragma unroll
      for (int rr = 0; rr < 4; ++rr) {
        const int row = mi * 16 + (l >> 4) * 4 + rr;
        const float mu = murs[row][0], rs = murs[row][1];
        float dp = 0.f;
#pragma unroll
        for (int ni = 0; ni < 8; ++ni) {
          const float x = acc[mi][ni][rr] + bcol[ni];
          dp += fmaxf((x - mu) * rs * gcol[ni] + becol[ni], 0.f) * wf[ni];
        }
#pragma unroll
        for (int o = 1; o < 16; o <<= 1) dp += __shfl_xor(dp, o, 64);
        if ((l & 15) == 0) part[w][row][0] = dp;
      }
    __syncthreads();
    if (tid < 64) {
      float dsum = 0.f;
#pragma unroll
      for (int ww = 0; ww < 8; ++ww) dsum += part[ww][tid][0];
      dotf[tid] = dsum;
    }
    __syncthreads();
#pragma unroll
    for (int it = 0; it < 8; ++it) {
      const int idx = tid + it * 512;
      const int row = idx >> 6, q = idx & 63;
      Qout[(size_t)(r0 + row) * NQ + q] = dotf[row] + qof[q];
    }
  }
#undef KT
#undef AF
#undef ISSUE_A
#undef ALOADX
#undef AWRX
#undef LOADB
#undef BAR
#undef WAITLGKM
#undef WAITVM16
}

extern "C" void kernel_launch(void* const* d_in, const int* in_sizes, int n_in,
                              void* d_out, int out_size, void* d_ws, size_t ws_size,
                              hipStream_t stream) {
  const float* state  = (const float*)d_in[0];
  const float* action = (const float*)d_in[1];
  const float* W1  = (const float*)d_in[2];
  const float* b1  = (const float*)d_in[3];
  const float* g1  = (const float*)d_in[4];
  const float* be1 = (const float*)d_in[5];
  const float* W2  = (const float*)d_in[6];
  const float* b2  = (const float*)d_in[7];
  const float* g2  = (const float*)d_in[8];
  const float* be2 = (const float*)d_in[9];
  const float* Wq1 = (const float*)d_in[10];
  const float* bq1 = (const float*)d_in[11];
  const float* Wq2 = (const float*)d_in[12];
  const float* bq2 = (const float*)d_in[13];
  const float* Wh  = (const float*)d_in[14];
  const float* bh  = (const float*)d_in[15];
  float* out = (float*)d_out;

  // workspace (~37 MB)
  char* ws = (char*)d_ws;
  size_t off = 0;
  float* qoff = (float*)(ws + off); off += 256;
  unsigned short* w1b = (unsigned short*)(ws + off); off += (size_t)HID * KDIM * 2;    // 1.18 MB
  unsigned short* w2b = (unsigned short*)(ws + off); off += (size_t)HID * HID * 2;     // 2.10 MB
  unsigned short* h1b = (unsigned short*)(ws + off);                                   // 33.55 MB

  (void)hipFuncSetAttribute((const void*)fused_k<true, false, KDIM / 64>,
                            hipFuncAttributeMaxDynamicSharedMemorySize, FK_LDS);
  (void)hipFuncSetAttribute((const void*)fused_k<false, true, HID / 64>,
                            hipFuncAttributeMaxDynamicSharedMemorySize, FK_LDS);

  prep_k<<<PREP_BLOCKS, 256, 0, stream>>>(W1, W2, Wq1, bq1, Wq2, bq2, Wh, bh,
                                          w1b, w2b, qoff);

  // layer 1: h1 = relu(LN(concat(state,action)@W1 + b1)) -> h1b (bf16)
  fused_k<true, false, KDIM / 64><<<B_ROWS / 64, 512, FK_LDS, stream>>>(
      state, action, nullptr, w1b, b1, g1, be1, nullptr, nullptr,
      h1b, nullptr, KDIM);
  // layer 2 + head: out = relu(LN(h1@W2 + b2)) @ Wf + qoff
  fused_k<false, true, HID / 64><<<B_ROWS / 64, 512, FK_LDS, stream>>>(
      nullptr, nullptr, h1b, w2b, b2, g2, be2, Wh, qoff,
      nullptr, out, HID);
}

// Round 15
// 115.126 us; speedup vs baseline: 1.3049x; 1.3049x over previous
//
#include <hip/hip_runtime.h>
#include <hip/hip_bf16.h>
#include <cstddef>

// Problem constants
#define B_ROWS 16384
#define SDIM 512
#define ADIM 64
#define KDIM 576    // SDIM + ADIM = 9 K-tiles of 64 (exact)
#define HID 1024
#define NQ 64

// prep: transposes + qoff only (x is consumed raw by fused1)
#define T1_BLOCKS ((KDIM / 32) * (HID / 32))   // 576
#define T2_BLOCKS ((HID / 32) * (HID / 32))    // 1024
#define PREP_BLOCKS (T1_BLOCKS + T2_BLOCKS + 1)

#define FK_LDS (16384 + 131072)   // A double-buffer (2x8KB) + B (8 waves x 16KB)

typedef __attribute__((ext_vector_type(8))) __bf16 bf16x8;
typedef __attribute__((ext_vector_type(4))) float f32x4;

static __device__ __forceinline__ float bf2f(unsigned short u) {
  union { unsigned int i; float f; } x; x.i = ((unsigned int)u) << 16; return x.f;
}
static __device__ __forceinline__ unsigned short f2bf(float f) {
  union { float f; unsigned int i; } x; x.f = f;
  unsigned int i = x.i + (0x7fffu + ((x.i >> 16) & 1u)); // RNE
  return (unsigned short)(i >> 16);
}

static __device__ __forceinline__ void gload_lds16(const unsigned short* g, unsigned short* l) {
  __builtin_amdgcn_global_load_lds(
      (const __attribute__((address_space(1))) void*)(const void*)g,
      (__attribute__((address_space(3))) void*)(void*)l, 16, 0, 0);
}

// pack 8 f32 -> 8 bf16 (RNE) in one uint4
static __device__ __forceinline__ uint4 pack8(float4 a, float4 b) {
  uint4 o;
  o.x = (unsigned)f2bf(a.x) | ((unsigned)f2bf(a.y) << 16);
  o.y = (unsigned)f2bf(a.z) | ((unsigned)f2bf(a.w) << 16);
  o.z = (unsigned)f2bf(b.x) | ((unsigned)f2bf(b.y) << 16);
  o.w = (unsigned)f2bf(b.z) | ((unsigned)f2bf(b.w) << 16);
  return o;
}

// ---- transpose helper: W [Kin][N] f32 -> Wb [N][Kin] bf16 ----
static __device__ __forceinline__ void transpose_body(
    const float* __restrict__ W, unsigned short* __restrict__ Wb,
    int Kin, int N, int k0, int n0, unsigned short* tile) {
  const int tx = threadIdx.x & 31, ty = threadIdx.x >> 5;
#pragma unroll
  for (int i = 0; i < 32; i += 8)
    tile[(ty + i) * 33 + tx] = f2bf(W[(size_t)(k0 + ty + i) * N + n0 + tx]);
  __syncthreads();
#pragma unroll
  for (int i = 0; i < 32; i += 8)
    Wb[(size_t)(n0 + ty + i) * Kin + k0 + tx] = tile[tx * 33 + ty + i];
}

// ---- prep: weight transposes + qoff ----
__global__ __launch_bounds__(256) void prep_k(
    const float* __restrict__ W1, const float* __restrict__ W2,
    const float* __restrict__ Wq1, const float* __restrict__ bq1,
    const float* __restrict__ Wq2, const float* __restrict__ bq2,
    const float* __restrict__ Wh, const float* __restrict__ bh,
    unsigned short* __restrict__ w1b, unsigned short* __restrict__ w2b,
    float* __restrict__ qoff) {
  __shared__ unsigned short tile[32 * 33];
  const int b = blockIdx.x;
  if (b < T1_BLOCKS) {
    transpose_body(W1, w1b, KDIM, HID, (b / 32) * 32, (b % 32) * 32, tile);
  } else if (b < T1_BLOCKS + T2_BLOCKS) {
    const int t = b - T1_BLOCKS;
    transpose_body(W2, w2b, HID, HID, (t / 32) * 32, (t % 32) * 32, tile);
  } else {
    const int q = threadIdx.x;
    if (q < NQ) {
      const float tau = ((float)q + 0.5f) * (1.0f / (float)NQ);
      float t1[64];
#pragma unroll
      for (int k = 0; k < 64; ++k) t1[k] = fmaxf(fmaf(tau, Wq1[k], bq1[k]), 0.f);
      float acc = bh[0];
#pragma unroll 1
      for (int j = 0; j < 64; ++j) {
        float t2 = bq2[j];
#pragma unroll
        for (int k = 0; k < 64; ++k) t2 = fmaf(t1[k], Wq2[k * 64 + j], t2);
        acc = fmaf(t2, Wh[HID + j], acc);
      }
      qoff[q] = acc;
    }
  }
}

// ============================================================================
// Pipelined row-stripe fused GEMM+LN (r13-measured skeleton, 48 us/layer).
// Round-15 change (fused1 / !FINAL only): COLUMN REMAP -- fragment ni reads
// LDS B-row (l&15)*8+ni instead of ni*16+(l&15), so each lane's acc holds 8
// CONTIGUOUS output cols (w*128+(l&15)*8..+7). The H-store then becomes one
// 16B uint4 per (mi,rr) instead of 8 scalar 2B stores (r13's hidden ~20us
// drain: 33.5MB in 32B segments). FINAL path byte-identical to r13.
// ============================================================================
template <bool XSRC, bool FINAL>
__global__ __launch_bounds__(512, 2) void fused_k(
    const float* __restrict__ Xs,           // state  [M][512]   (XSRC)
    const float* __restrict__ Xa,           // action [M][64]    (XSRC)
    const unsigned short* __restrict__ A,   // [M][K] bf16       (!XSRC)
    const unsigned short* __restrict__ Bt,  // [1024][K] bf16 (W transposed)
    const float* __restrict__ bias, const float* __restrict__ g,
    const float* __restrict__ be, const float* __restrict__ Wh,
    const float* __restrict__ qoff,
    unsigned short* __restrict__ Hout, float* __restrict__ Qout,
    int K, int NT) {
  extern __shared__ unsigned short sm[];
  __shared__ float part[8][64][2];
  __shared__ float murs[64][2];
  __shared__ float dotf[64];
  __shared__ float qof[64];

  const int tid = threadIdx.x;
  const int w = tid >> 6, l = tid & 63;
  const int r0 = (int)blockIdx.x * 64;
  const int sb = (int)blockIdx.x % NT;          // K-order stagger

  const int sce = ((((l & 7) << 4) ^ (((l >> 3) & 4) << 3)) >> 1);
  const int lr = (l & 15) << 7;
  const int cSw = (((l >> 4) << 4) ^ ((l & 4) << 3));

  f32x4 acc[4][8] = {};
  float4 ar0, ar1;   // XSRC: next A-tile f32 in flight (8 floats/lane)

#define KT(x) ((((x) + sb) % NT) << 6)
#define AF(d, mi, kk) (*(const bf16x8*)(sm + (((d)*8192 + (mi)*2048 + lr + cSw + ((kk) << 6)) >> 1)))
// B-frag row: FINAL keeps r13 mapping; !FINAL remaps for contiguous out-cols.
#define BROW(ni) (FINAL ? ((ni) * 16 + (l & 15)) : ((l & 15) * 8 + (ni)))
#define BXOR(ni) (FINAL ? ((l & 4) << 3) : (((ni) & 4) << 3))
#define BFW(ni, kk) (*(const bf16x8*)(sm + ((16384 + w*16384 + BROW(ni)*128 + (((l >> 4) << 4) ^ BXOR(ni)) + ((kk) << 6)) >> 1)))
#define ISSUE_A(d, kt) \
    gload_lds16(A + (size_t)(r0 + w * 8 + (l >> 3)) * K + (kt) + sce, \
                sm + (((d)*8192 + w * 1024) >> 1))
#define ALOADX(kt) do { \
    const int row_ = r0 + w * 8 + (l >> 3); \
    if ((kt) < SDIM) { const float* p_ = Xs + (size_t)row_ * SDIM + (kt) + sce; \
      ar0 = *(const float4*)p_; ar1 = *(const float4*)(p_ + 4); } \
    else { const float* p_ = Xa + (size_t)row_ * ADIM + ((kt) - SDIM) + sce; \
      ar0 = *(const float4*)p_; ar1 = *(const float4*)(p_ + 4); } } while (0)
#define AWRX(d) (*(uint4*)(sm + (((d)*8192 + w * 1024 + l * 16) >> 1)) = pack8(ar0, ar1))
#define ISSUE_B(kt) do { _Pragma("unroll") for (int i_ = 0; i_ < 16; ++i_) \
    gload_lds16(Bt + (size_t)(w * 128 + i_ * 8 + (l >> 3)) * K + (kt) + sce, \
                sm + ((16384 + w * 16384 + i_ * 1024) >> 1)); } while (0)
#define BAR() __builtin_amdgcn_s_barrier()
#define WAITLGKM() asm volatile("s_waitcnt lgkmcnt(0)" ::: "memory")
#define WAITVM(n) asm volatile("s_waitcnt vmcnt(" #n ")" ::: "memory")

  // prologue
  if (XSRC) {
    ALOADX(KT(0)); AWRX(0);          // serial load->cvt->write for tile 0
    ISSUE_B(KT(0));
    if (NT > 1) ALOADX(KT(1));       // A(1) f32 regs in flight
    WAITLGKM(); BAR();               // commit abuf0; B(0)+A(1) outstanding
  } else {
    ISSUE_A(0, KT(0));
    ISSUE_B(KT(0));
    ISSUE_A(1, KT(1));
    WAITVM(17); BAR();               // drain A(0) write only
  }

  for (int t = 0; t < NT; ++t) {
    const int d = t & 1;
    // entry: drain B(t), keep next-A in flight
    if (t + 1 < NT) { if (XSRC) { WAITVM(2); } else { WAITVM(1); } }
    else { WAITVM(0); }
    bf16x8 af[4], bfr[8];
    // kk = 0
#pragma unroll
    for (int mi = 0; mi < 4; ++mi) af[mi] = AF(d, mi, 0);
#pragma unroll
    for (int ni = 0; ni < 8; ++ni) bfr[ni] = BFW(ni, 0);
    __builtin_amdgcn_s_setprio(1);
#pragma unroll
    for (int mi = 0; mi < 4; ++mi)
#pragma unroll
      for (int ni = 0; ni < 8; ++ni)
        acc[mi][ni] = __builtin_amdgcn_mfma_f32_16x16x32_bf16(af[mi], bfr[ni], acc[mi][ni], 0, 0, 0);
    __builtin_amdgcn_s_setprio(0);
    // kk = 1
#pragma unroll
    for (int mi = 0; mi < 4; ++mi) af[mi] = AF(d, mi, 1);
#pragma unroll
    for (int ni = 0; ni < 8; ++ni) bfr[ni] = BFW(ni, 1);
    WAITLGKM();                           // tile-t LDS reads landed
    if (t + 1 < NT) ISSUE_B(KT(t + 1));   // wave-private overwrite, safe
    if (XSRC && t + 1 < NT) AWRX((t + 1) & 1);  // cvt+write A(t+1); auto-waits A-regs
    __builtin_amdgcn_s_setprio(1);
#pragma unroll
    for (int mi = 0; mi < 4; ++mi)
#pragma unroll
      for (int ni = 0; ni < 8; ++ni)
        acc[mi][ni] = __builtin_amdgcn_mfma_f32_16x16x32_bf16(af[mi], bfr[ni], acc[mi][ni], 0, 0, 0);
    __builtin_amdgcn_s_setprio(0);
    if (XSRC) {
      if (t + 1 < NT) { WAITLGKM(); }     // commit AWRX ds_write pre-barrier
      BAR();
      if (t + 2 < NT) ALOADX(KT(t + 2));  // next A f32 regs, post-barrier
    } else {
      if (t + 1 < NT) { WAITVM(16); }     // drain own A(t+1) glds write
      BAR();
      if (t + 2 < NT) ISSUE_A(d, KT(t + 2));
    }
  }

  // ---------------- epilogue ----------------
  // !FINAL col ownership (remapped): lane l owns cols cb..cb+7 CONTIGUOUS,
  //   cb = w*128 + (l&15)*8. FINAL (r13 mapping): col = w*128 + ni*16 + (l&15).
  float bcol[8], gcol[8], becol[8];
  const int cb = w * 128 + (l & 15) * 8;
  if (!FINAL) {
    *(float4*)&bcol[0]  = *(const float4*)(bias + cb);
    *(float4*)&bcol[4]  = *(const float4*)(bias + cb + 4);
    *(float4*)&gcol[0]  = *(const float4*)(g + cb);
    *(float4*)&gcol[4]  = *(const float4*)(g + cb + 4);
    *(float4*)&becol[0] = *(const float4*)(be + cb);
    *(float4*)&becol[4] = *(const float4*)(be + cb + 4);
  } else {
#pragma unroll
    for (int ni = 0; ni < 8; ++ni) {
      const int col = w * 128 + ni * 16 + (l & 15);
      bcol[ni] = bias[col];
      gcol[ni] = g[col];
      becol[ni] = be[col];
    }
  }
#pragma unroll
  for (int mi = 0; mi < 4; ++mi)
#pragma unroll
    for (int rr = 0; rr < 4; ++rr) {
      float s1 = 0.f, s2 = 0.f;
#pragma unroll
      for (int ni = 0; ni < 8; ++ni) {
        const float x = acc[mi][ni][rr] + bcol[ni];
        s1 += x; s2 += x * x;
      }
#pragma unroll
      for (int o = 1; o < 16; o <<= 1) {
        s1 += __shfl_xor(s1, o, 64);
        s2 += __shfl_xor(s2, o, 64);
      }
      if ((l & 15) == 0) {
        const int row = mi * 16 + (l >> 4) * 4 + rr;
        part[w][row][0] = s1;
        part[w][row][1] = s2;
      }
    }
  __syncthreads();
  if (tid < 64) {
    float s1 = 0.f, s2 = 0.f;
#pragma unroll
    for (int ww = 0; ww < 8; ++ww) { s1 += part[ww][tid][0]; s2 += part[ww][tid][1]; }
    const float mu = s1 * (1.0f / HID);
    murs[tid][0] = mu;
    murs[tid][1] = rsqrtf(s2 * (1.0f / HID) - mu * mu + 1e-5f);
    if (FINAL) qof[tid] = qoff[tid];
  }
  __syncthreads();

  if (!FINAL) {
    // vectorized H-store: one 16B uint4 per (mi,rr); 256B segments/16 lanes
#pragma unroll
    for (int mi = 0; mi < 4; ++mi)
#pragma unroll
      for (int rr = 0; rr < 4; ++rr) {
        const int row = mi * 16 + (l >> 4) * 4 + rr;
        const float mu = murs[row][0], rs = murs[row][1];
        uint4 ov;
        unsigned int* op = (unsigned int*)&ov;
#pragma unroll
        for (int i = 0; i < 4; ++i) {
          const float y0 = fmaxf((acc[mi][2 * i][rr] + bcol[2 * i] - mu) * rs * gcol[2 * i] + becol[2 * i], 0.f);
          const float y1 = fmaxf((acc[mi][2 * i + 1][rr] + bcol[2 * i + 1] - mu) * rs * gcol[2 * i + 1] + becol[2 * i + 1], 0.f);
          op[i] = (unsigned)f2bf(y0) | ((unsigned)f2bf(y1) << 16);
        }
        *(uint4*)(Hout + (size_t)(r0 + row) * HID + cb) = ov;
      }
  } else {
    float wf[8];
#pragma unroll
    for (int ni = 0; ni < 8; ++ni) wf[ni] = Wh[w * 128 + ni * 16 + (l & 15)];
#pragma unroll
    for (int mi = 0; mi < 4; ++mi)
#pragma unroll
      for (int rr = 0; rr < 4; ++rr) {
        const int row = mi * 16 + (l >> 4) * 4 + rr;
        const float mu = murs[row][0], rs = murs[row][1];
        float dp = 0.f;
#pragma unroll
        for (int ni = 0; ni < 8; ++ni) {
          const float x = acc[mi][ni][rr] + bcol[ni];
          dp += fmaxf((x - mu) * rs * gcol[ni] + becol[ni], 0.f) * wf[ni];
        }
#pragma unroll
        for (int o = 1; o < 16; o <<= 1) dp += __shfl_xor(dp, o, 64);
        if ((l & 15) == 0) part[w][row][0] = dp;
      }
    __syncthreads();
    if (tid < 64) {
      float dsum = 0.f;
#pragma unroll
      for (int ww = 0; ww < 8; ++ww) dsum += part[ww][tid][0];
      dotf[tid] = dsum;
    }
    __syncthreads();
#pragma unroll
    for (int it = 0; it < 8; ++it) {
      const int idx = tid + it * 512;
      const int row = idx >> 6, q = idx & 63;
      Qout[(size_t)(r0 + row) * NQ + q] = dotf[row] + qof[q];
    }
  }
#undef KT
#undef AF
#undef BROW
#undef BXOR
#undef BFW
#undef ISSUE_A
#undef ALOADX
#undef AWRX
#undef ISSUE_B
#undef BAR
#undef WAITLGKM
#undef WAITVM
}

extern "C" void kernel_launch(void* const* d_in, const int* in_sizes, int n_in,
                              void* d_out, int out_size, void* d_ws, size_t ws_size,
                              hipStream_t stream) {
  const float* state  = (const float*)d_in[0];
  const float* action = (const float*)d_in[1];
  const float* W1  = (const float*)d_in[2];
  const float* b1  = (const float*)d_in[3];
  const float* g1  = (const float*)d_in[4];
  const float* be1 = (const float*)d_in[5];
  const float* W2  = (const float*)d_in[6];
  const float* b2  = (const float*)d_in[7];
  const float* g2  = (const float*)d_in[8];
  const float* be2 = (const float*)d_in[9];
  const float* Wq1 = (const float*)d_in[10];
  const float* bq1 = (const float*)d_in[11];
  const float* Wq2 = (const float*)d_in[12];
  const float* bq2 = (const float*)d_in[13];
  const float* Wh  = (const float*)d_in[14];
  const float* bh  = (const float*)d_in[15];
  float* out = (float*)d_out;

  // workspace (~37 MB)
  char* ws = (char*)d_ws;
  size_t off = 0;
  float* qoff = (float*)(ws + off); off += 256;
  unsigned short* w1b = (unsigned short*)(ws + off); off += (size_t)HID * KDIM * 2;    // 1.18 MB
  unsigned short* w2b = (unsigned short*)(ws + off); off += (size_t)HID * HID * 2;     // 2.10 MB
  unsigned short* h1b = (unsigned short*)(ws + off);                                   // 33.55 MB

  (void)hipFuncSetAttribute((const void*)fused_k<true, false>, hipFuncAttributeMaxDynamicSharedMemorySize, FK_LDS);
  (void)hipFuncSetAttribute((const void*)fused_k<false, true>, hipFuncAttributeMaxDynamicSharedMemorySize, FK_LDS);

  prep_k<<<PREP_BLOCKS, 256, 0, stream>>>(W1, W2, Wq1, bq1, Wq2, bq2, Wh, bh,
                                          w1b, w2b, qoff);

  // layer 1: h1 = relu(LN(concat(state,action)@W1 + b1)) -> h1b (bf16)
  fused_k<true, false><<<B_ROWS / 64, 512, FK_LDS, stream>>>(
      state, action, nullptr, w1b, b1, g1, be1, nullptr, nullptr,
      h1b, nullptr, KDIM, KDIM / 64);
  // layer 2 + head: out = relu(LN(h1@W2 + b2)) @ Wf + qoff
  fused_k<false, true><<<B_ROWS / 64, 512, FK_LDS, stream>>>(
      nullptr, nullptr, h1b, w2b, b2, g2, be2, Wh, qoff,
      nullptr, out, HID, HID / 64);
}

// Round 16
// 107.430 us; speedup vs baseline: 1.3984x; 1.0716x over previous
//
#include <hip/hip_runtime.h>
#include <hip/hip_bf16.h>
#include <cstddef>

// Problem constants
#define B_ROWS 16384
#define SDIM 512
#define ADIM 64
#define KDIM 576    // SDIM + ADIM = 9 K-tiles of 64 (exact)
#define HID 1024
#define NQ 64
#define NT1 9
#define NT2 16

// prep: transposes + qoff
#define T1_BLOCKS ((KDIM / 32) * (HID / 32))   // 576
#define T2_BLOCKS ((HID / 32) * (HID / 32))    // 1024
#define PREP_BLOCKS (T1_BLOCKS + T2_BLOCKS + 1)

#define FK_LDS (16384 + 131072)   // A double-buffer (2x8KB) + B1/h1 region (128KB)

typedef __attribute__((ext_vector_type(8))) __bf16 bf16x8;
typedef __attribute__((ext_vector_type(4))) float f32x4;

static __device__ __forceinline__ float bf2f(unsigned short u) {
  union { unsigned int i; float f; } x; x.i = ((unsigned int)u) << 16; return x.f;
}
static __device__ __forceinline__ unsigned short f2bf(float f) {
  union { float f; unsigned int i; } x; x.f = f;
  unsigned int i = x.i + (0x7fffu + ((x.i >> 16) & 1u)); // RNE
  return (unsigned short)(i >> 16);
}

static __device__ __forceinline__ void gload_lds16(const unsigned short* g, unsigned short* l) {
  __builtin_amdgcn_global_load_lds(
      (const __attribute__((address_space(1))) void*)(const void*)g,
      (__attribute__((address_space(3))) void*)(void*)l, 16, 0, 0);
}

// pack 8 f32 -> 8 bf16 (RNE) in one uint4
static __device__ __forceinline__ uint4 pack8(float4 a, float4 b) {
  uint4 o;
  o.x = (unsigned)f2bf(a.x) | ((unsigned)f2bf(a.y) << 16);
  o.y = (unsigned)f2bf(a.z) | ((unsigned)f2bf(a.w) << 16);
  o.z = (unsigned)f2bf(b.x) | ((unsigned)f2bf(b.y) << 16);
  o.w = (unsigned)f2bf(b.z) | ((unsigned)f2bf(b.w) << 16);
  return o;
}

// ---- transpose helper: W [Kin][N] f32 -> Wb [N][Kin] bf16 ----
static __device__ __forceinline__ void transpose_body(
    const float* __restrict__ W, unsigned short* __restrict__ Wb,
    int Kin, int N, int k0, int n0, unsigned short* tile) {
  const int tx = threadIdx.x & 31, ty = threadIdx.x >> 5;
#pragma unroll
  for (int i = 0; i < 32; i += 8)
    tile[(ty + i) * 33 + tx] = f2bf(W[(size_t)(k0 + ty + i) * N + n0 + tx]);
  __syncthreads();
#pragma unroll
  for (int i = 0; i < 32; i += 8)
    Wb[(size_t)(n0 + ty + i) * Kin + k0 + tx] = tile[tx * 33 + ty + i];
}

// ---- prep: weight transposes + qoff ----
__global__ __launch_bounds__(256) void prep_k(
    const float* __restrict__ W1, const float* __restrict__ W2,
    const float* __restrict__ Wq1, const float* __restrict__ bq1,
    const float* __restrict__ Wq2, const float* __restrict__ bq2,
    const float* __restrict__ Wh, const float* __restrict__ bh,
    unsigned short* __restrict__ w1b, unsigned short* __restrict__ w2b,
    float* __restrict__ qoff) {
  __shared__ unsigned short tile[32 * 33];
  const int b = blockIdx.x;
  if (b < T1_BLOCKS) {
    transpose_body(W1, w1b, KDIM, HID, (b / 32) * 32, (b % 32) * 32, tile);
  } else if (b < T1_BLOCKS + T2_BLOCKS) {
    const int t = b - T1_BLOCKS;
    transpose_body(W2, w2b, HID, HID, (t / 32) * 32, (t % 32) * 32, tile);
  } else {
    const int q = threadIdx.x;
    if (q < NQ) {
      const float tau = ((float)q + 0.5f) * (1.0f / (float)NQ);
      float t1[64];
#pragma unroll
      for (int k = 0; k < 64; ++k) t1[k] = fmaxf(fmaf(tau, Wq1[k], bq1[k]), 0.f);
      float acc = bh[0];
#pragma unroll 1
      for (int j = 0; j < 64; ++j) {
        float t2 = bq2[j];
#pragma unroll
        for (int k = 0; k < 64; ++k) t2 = fmaf(t1[k], Wq2[k * 64 + j], t2);
        acc = fmaf(t2, Wh[HID + j], acc);
      }
      qoff[q] = acc;
    }
  }
}

// ---- w2c permute: w2b [N][K] -> fragment-contiguous layout ----
// frag chunk idx c = ((w*NT2 + t)*2 + kk)*8 + ni ; chunk = 64 lanes x 16B.
// lane l's 16B = w2b[w*128 + ni*16 + (l&15)][t*64 + kk*32 + (l>>4)*8 .. +7]
__global__ __launch_bounds__(256) void w2perm_k(
    const unsigned short* __restrict__ w2b, unsigned short* __restrict__ w2c) {
  const int gt = blockIdx.x * 256 + threadIdx.x;   // 131072 threads
  const int c = gt >> 6, l = gt & 63;
  const int ni = c & 7, kk = (c >> 3) & 1, t = (c >> 4) & 15, w = c >> 8;
  const int row = w * 128 + ni * 16 + (l & 15);
  const int kcol = t * 64 + kk * 32 + ((l >> 4) << 3);
  *(uint4*)(w2c + (size_t)gt * 8) = *(const uint4*)(w2b + (size_t)row * HID + kcol);
}

// ============================================================================
// WHOLE-NETWORK single kernel. Block = 64 rows x all 1024 cols, 8 waves.
// Phase 1 (r13-measured XSRC loop, r15-verified remapped B-frags): layer-1
//   GEMM; LN1+ReLU epilogue writes h1 (bf16) into the wave's own B-chunk of
//   LDS (wave-private overwrite; one barrier publishes). h1 never hits HBM.
// Phase 2: layer-2 GEMM with A-frags from resident LDS (no staging, NO
//   barriers) and W2 streamed global->reg from fragment-contiguous w2c
//   (each lane: one coalesced 16B load per frag; 4-frag groups, 1-group
//   lookahead to bound VGPR at ~240 unified). FINAL epilogue (r13-verified):
//   LN2+ReLU row-dot Wf + qoff -> f32 out.
// h1 LDS map (derived, writer==reader): chunk w = cols w*128..+127 = layer-2
//   k-tiles 2w,2w+1. byte = 16384 + w*16384 + ((l&15)>>3)*8192 + row*128 +
//   (((l&7)*16) ^ ((row&4)<<3)); reader AF2 XORs the same byte-bit-5 by
//   row-bit-2 (cSw), k-correspondence (l&15)*8+j == sub*64+slot*8+j.
// ============================================================================
__global__ __launch_bounds__(512, 2) void fused_all_k(
    const float* __restrict__ Xs, const float* __restrict__ Xa,
    const unsigned short* __restrict__ B1t,  // w1b [1024][576]
    const unsigned short* __restrict__ w2c,  // frag-contiguous W2 (2MB)
    const float* __restrict__ b1, const float* __restrict__ g1,
    const float* __restrict__ be1,
    const float* __restrict__ b2, const float* __restrict__ g2,
    const float* __restrict__ be2,
    const float* __restrict__ Wh, const float* __restrict__ qoff,
    float* __restrict__ Qout) {
  extern __shared__ unsigned short sm[];
  __shared__ float part[8][64][2];
  __shared__ float murs[64][2];
  __shared__ float dotf[64];
  __shared__ float qof[64];

  const int tid = threadIdx.x;
  const int w = tid >> 6, l = tid & 63;
  const int r0 = (int)blockIdx.x * 64;
  const int sb = (int)blockIdx.x % NT1;     // phase-1 K stagger

  const int sce = ((((l & 7) << 4) ^ (((l >> 3) & 4) << 3)) >> 1);
  const int lr = (l & 15) << 7;
  const int cSw = (((l >> 4) << 4) ^ ((l & 4) << 3));

  f32x4 acc[4][8] = {};
  float4 ar0, ar1;

#define KT(x) ((((x) + sb) % NT1) << 6)
#define AF1(d, mi, kk) (*(const bf16x8*)(sm + (((d)*8192 + (mi)*2048 + lr + cSw + ((kk) << 6)) >> 1)))
// remapped B1 frag (r15-verified): lane owns 8 contiguous out-cols
#define BF1(ni, kk) (*(const bf16x8*)(sm + ((16384 + w*16384 + ((l & 15) * 8 + (ni)) * 128 + (((l >> 4) << 4) ^ (((ni) & 4) << 3)) + ((kk) << 6)) >> 1)))
#define ALOADX(kt) do { \
    const int row_ = r0 + w * 8 + (l >> 3); \
    if ((kt) < SDIM) { const float* p_ = Xs + (size_t)row_ * SDIM + (kt) + sce; \
      ar0 = *(const float4*)p_; ar1 = *(const float4*)(p_ + 4); } \
    else { const float* p_ = Xa + (size_t)row_ * ADIM + ((kt) - SDIM) + sce; \
      ar0 = *(const float4*)p_; ar1 = *(const float4*)(p_ + 4); } } while (0)
#define AWRX(d) (*(uint4*)(sm + (((d)*8192 + w * 1024 + l * 16) >> 1)) = pack8(ar0, ar1))
#define ISSUE_B1(kt) do { _Pragma("unroll") for (int i_ = 0; i_ < 16; ++i_) \
    gload_lds16(B1t + (size_t)(w * 128 + i_ * 8 + (l >> 3)) * KDIM + (kt) + sce, \
                sm + ((16384 + w * 16384 + i_ * 1024) >> 1)); } while (0)
// phase-2 A frag from resident h1 LDS
#define AF2(t, mi, kk) (*(const bf16x8*)(sm + ((16384 + ((t) >> 1) * 16384 + ((t) & 1) * 8192 + (mi)*2048 + lr + cSw + ((kk) << 6)) >> 1)))
// phase-2 B 4-frag group load: ni = h*4+j
#define LOADB2H(dst, t, kk, h) do { _Pragma("unroll") for (int j_ = 0; j_ < 4; ++j_) \
    dst[j_] = *(const bf16x8*)(w2c + ((size_t)((((w * NT2 + (t)) * 2 + (kk)) * 8 + (h) * 4 + j_) * 64 + l) * 8)); } while (0)
#define MQ1(bsrc) do { _Pragma("unroll") for (int mi = 0; mi < 4; ++mi) \
    _Pragma("unroll") for (int ni = 0; ni < 8; ++ni) \
      acc[mi][ni] = __builtin_amdgcn_mfma_f32_16x16x32_bf16(af[mi], bsrc[ni], acc[mi][ni], 0, 0, 0); } while (0)
#define MQ2(cv, NO) do { _Pragma("unroll") for (int mi = 0; mi < 4; ++mi) \
    _Pragma("unroll") for (int j_ = 0; j_ < 4; ++j_) \
      acc[mi][(NO) + j_] = __builtin_amdgcn_mfma_f32_16x16x32_bf16(af2[mi], cv[j_], acc[mi][(NO) + j_], 0, 0, 0); } while (0)
#define BAR() __builtin_amdgcn_s_barrier()
#define WAITLGKM() asm volatile("s_waitcnt lgkmcnt(0)" ::: "memory")
#define WAITVM(n) asm volatile("s_waitcnt vmcnt(" #n ")" ::: "memory")
#define PRIO1() __builtin_amdgcn_s_setprio(1)
#define PRIO0() __builtin_amdgcn_s_setprio(0)

  // ---------------- phase 1: layer-1 GEMM (r13 XSRC skeleton) ----------------
  ALOADX(KT(0)); AWRX(0);
  ISSUE_B1(KT(0));
  ALOADX(KT(1));
  WAITLGKM(); BAR();

  for (int t = 0; t < NT1; ++t) {
    const int d = t & 1;
    if (t + 1 < NT1) { WAITVM(2); } else { WAITVM(0); }
    bf16x8 af[4], bfr[8];
#pragma unroll
    for (int mi = 0; mi < 4; ++mi) af[mi] = AF1(d, mi, 0);
#pragma unroll
    for (int ni = 0; ni < 8; ++ni) bfr[ni] = BF1(ni, 0);
    PRIO1(); MQ1(bfr); PRIO0();
#pragma unroll
    for (int mi = 0; mi < 4; ++mi) af[mi] = AF1(d, mi, 1);
#pragma unroll
    for (int ni = 0; ni < 8; ++ni) bfr[ni] = BF1(ni, 1);
    WAITLGKM();
    if (t + 1 < NT1) ISSUE_B1(KT(t + 1));
    if (t + 1 < NT1) AWRX((t + 1) & 1);
    PRIO1(); MQ1(bfr); PRIO0();
    if (t + 1 < NT1) { WAITLGKM(); }
    BAR();
    if (t + 2 < NT1) ALOADX(KT(t + 2));
  }

  // ---------------- epilogue 1: LN1+ReLU -> h1 into LDS ----------------
  float bcol[8], gcol[8], becol[8];
  const int cb = w * 128 + (l & 15) * 8;   // 8 contiguous cols (remap)
  *(float4*)&bcol[0]  = *(const float4*)(b1 + cb);
  *(float4*)&bcol[4]  = *(const float4*)(b1 + cb + 4);
  *(float4*)&gcol[0]  = *(const float4*)(g1 + cb);
  *(float4*)&gcol[4]  = *(const float4*)(g1 + cb + 4);
  *(float4*)&becol[0] = *(const float4*)(be1 + cb);
  *(float4*)&becol[4] = *(const float4*)(be1 + cb + 4);
#pragma unroll
  for (int mi = 0; mi < 4; ++mi)
#pragma unroll
    for (int rr = 0; rr < 4; ++rr) {
      float s1 = 0.f, s2 = 0.f;
#pragma unroll
      for (int ni = 0; ni < 8; ++ni) {
        const float x = acc[mi][ni][rr] + bcol[ni];
        s1 += x; s2 += x * x;
      }
#pragma unroll
      for (int o = 1; o < 16; o <<= 1) {
        s1 += __shfl_xor(s1, o, 64);
        s2 += __shfl_xor(s2, o, 64);
      }
      if ((l & 15) == 0) {
        const int row = mi * 16 + (l >> 4) * 4 + rr;
        part[w][row][0] = s1;
        part[w][row][1] = s2;
      }
    }
  __syncthreads();
  if (tid < 64) {
    float s1 = 0.f, s2 = 0.f;
#pragma unroll
    for (int ww = 0; ww < 8; ++ww) { s1 += part[ww][tid][0]; s2 += part[ww][tid][1]; }
    const float mu = s1 * (1.0f / HID);
    murs[tid][0] = mu;
    murs[tid][1] = rsqrtf(s2 * (1.0f / HID) - mu * mu + 1e-5f);
    qof[tid] = qoff[tid];
  }
  __syncthreads();
  // h1 write: wave-private chunk, A-frag-ready layout
#pragma unroll
  for (int mi = 0; mi < 4; ++mi)
#pragma unroll
    for (int rr = 0; rr < 4; ++rr) {
      const int row = mi * 16 + (l >> 4) * 4 + rr;
      const float mu = murs[row][0], rs = murs[row][1];
      uint4 ov;
      unsigned int* op = (unsigned int*)&ov;
#pragma unroll
      for (int i = 0; i < 4; ++i) {
        const float y0 = fmaxf((acc[mi][2 * i][rr] + bcol[2 * i] - mu) * rs * gcol[2 * i] + becol[2 * i], 0.f);
        const float y1 = fmaxf((acc[mi][2 * i + 1][rr] + bcol[2 * i + 1] - mu) * rs * gcol[2 * i + 1] + becol[2 * i + 1], 0.f);
        op[i] = (unsigned)f2bf(y0) | ((unsigned)f2bf(y1) << 16);
      }
      *(uint4*)(sm + ((16384 + w * 16384 + ((l & 15) >> 3) * 8192 + row * 128
                       + (((l & 7) * 16) ^ ((row & 4) << 3))) >> 1)) = ov;
    }
  __syncthreads();

  // ---------------- phase 2: layer-2 GEMM, barrier-free ----------------
#pragma unroll
  for (int mi = 0; mi < 4; ++mi)
#pragma unroll
    for (int ni = 0; ni < 8; ++ni) acc[mi][ni] = (f32x4){0.f, 0.f, 0.f, 0.f};

  {
    bf16x8 ca[4], cbf[4], af2[4];
    LOADB2H(ca, 0, 0, 0);
    for (int t = 0; t < NT2; ++t) {
#pragma unroll
      for (int mi = 0; mi < 4; ++mi) af2[mi] = AF2(t, mi, 0);
      LOADB2H(cbf, t, 0, 1);
      PRIO1(); MQ2(ca, 0); PRIO0();
      LOADB2H(ca, t, 1, 0);
      PRIO1(); MQ2(cbf, 4); PRIO0();
#pragma unroll
      for (int mi = 0; mi < 4; ++mi) af2[mi] = AF2(t, mi, 1);
      LOADB2H(cbf, t, 1, 1);
      PRIO1(); MQ2(ca, 0); PRIO0();
      if (t + 1 < NT2) LOADB2H(ca, t + 1, 0, 0);
      PRIO1(); MQ2(cbf, 4); PRIO0();
    }
  }

  // ---------------- epilogue 2: LN2+ReLU + Wf-dot + qoff (r13 FINAL) -------
  float b2c[8], g2c[8], be2c[8], wf[8];
#pragma unroll
  for (int ni = 0; ni < 8; ++ni) {
    const int col = w * 128 + ni * 16 + (l & 15);
    b2c[ni] = b2[col];
    g2c[ni] = g2[col];
    be2c[ni] = be2[col];
    wf[ni] = Wh[col];
  }
#pragma unroll
  for (int mi = 0; mi < 4; ++mi)
#pragma unroll
    for (int rr = 0; rr < 4; ++rr) {
      float s1 = 0.f, s2 = 0.f;
#pragma unroll
      for (int ni = 0; ni < 8; ++ni) {
        const float x = acc[mi][ni][rr] + b2c[ni];
        s1 += x; s2 += x * x;
      }
#pragma unroll
      for (int o = 1; o < 16; o <<= 1) {
        s1 += __shfl_xor(s1, o, 64);
        s2 += __shfl_xor(s2, o, 64);
      }
      if ((l & 15) == 0) {
        const int row = mi * 16 + (l >> 4) * 4 + rr;
        part[w][row][0] = s1;
        part[w][row][1] = s2;
      }
    }
  __syncthreads();
  if (tid < 64) {
    float s1 = 0.f, s2 = 0.f;
#pragma unroll
    for (int ww = 0; ww < 8; ++ww) { s1 += part[ww][tid][0]; s2 += part[ww][tid][1]; }
    const float mu = s1 * (1.0f / HID);
    murs[tid][0] = mu;
    murs[tid][1] = rsqrtf(s2 * (1.0f / HID) - mu * mu + 1e-5f);
  }
  __syncthreads();
#pragma unroll
  for (int mi = 0; mi < 4; ++mi)
#pragma unroll
    for (int rr = 0; rr < 4; ++rr) {
      const int row = mi * 16 + (l >> 4) * 4 + rr;
      const float mu = murs[row][0], rs = murs[row][1];
      float dp = 0.f;
#pragma unroll
      for (int ni = 0; ni < 8; ++ni) {
        const float x = acc[mi][ni][rr] + b2c[ni];
        dp += fmaxf((x - mu) * rs * g2c[ni] + be2c[ni], 0.f) * wf[ni];
      }
#pragma unroll
      for (int o = 1; o < 16; o <<= 1) dp += __shfl_xor(dp, o, 64);
      if ((l & 15) == 0) part[w][row][0] = dp;
    }
  __syncthreads();
  if (tid < 64) {
    float dsum = 0.f;
#pragma unroll
    for (int ww = 0; ww < 8; ++ww) dsum += part[ww][tid][0];
    dotf[tid] = dsum;
  }
  __syncthreads();
#pragma unroll
  for (int it = 0; it < 8; ++it) {
    const int idx = tid + it * 512;
    const int row = idx >> 6, q = idx & 63;
    Qout[(size_t)(r0 + row) * NQ + q] = dotf[row] + qof[q];
  }
#undef KT
#undef AF1
#undef BF1
#undef ALOADX
#undef AWRX
#undef ISSUE_B1
#undef AF2
#undef LOADB2H
#undef MQ1
#undef MQ2
#undef BAR
#undef WAITLGKM
#undef WAITVM
}

extern "C" void kernel_launch(void* const* d_in, const int* in_sizes, int n_in,
                              void* d_out, int out_size, void* d_ws, size_t ws_size,
                              hipStream_t stream) {
  const float* state  = (const float*)d_in[0];
  const float* action = (const float*)d_in[1];
  const float* W1  = (const float*)d_in[2];
  const float* b1  = (const float*)d_in[3];
  const float* g1  = (const float*)d_in[4];
  const float* be1 = (const float*)d_in[5];
  const float* W2  = (const float*)d_in[6];
  const float* b2  = (const float*)d_in[7];
  const float* g2  = (const float*)d_in[8];
  const float* be2 = (const float*)d_in[9];
  const float* Wq1 = (const float*)d_in[10];
  const float* bq1 = (const float*)d_in[11];
  const float* Wq2 = (const float*)d_in[12];
  const float* bq2 = (const float*)d_in[13];
  const float* Wh  = (const float*)d_in[14];
  const float* bh  = (const float*)d_in[15];
  float* out = (float*)d_out;

  // workspace (~5.3 MB)
  char* ws = (char*)d_ws;
  size_t off = 0;
  float* qoff = (float*)(ws + off); off += 256;
  unsigned short* w1b = (unsigned short*)(ws + off); off += (size_t)HID * KDIM * 2;  // 1.18 MB
  unsigned short* w2b = (unsigned short*)(ws + off); off += (size_t)HID * HID * 2;   // 2.10 MB
  unsigned short* w2c = (unsigned short*)(ws + off);                                 // 2.00 MB

  (void)hipFuncSetAttribute((const void*)fused_all_k,
                            hipFuncAttributeMaxDynamicSharedMemorySize, FK_LDS);

  prep_k<<<PREP_BLOCKS, 256, 0, stream>>>(W1, W2, Wq1, bq1, Wq2, bq2, Wh, bh,
                                          w1b, w2b, qoff);
  w2perm_k<<<512, 256, 0, stream>>>(w2b, w2c);

  fused_all_k<<<B_ROWS / 64, 512, FK_LDS, stream>>>(
      state, action, w1b, w2c, b1, g1, be1, b2, g2, be2, Wh, qoff, out);
}

// Round 17
// 106.859 us; speedup vs baseline: 1.4059x; 1.0053x over previous
//
#include <hip/hip_runtime.h>
#include <hip/hip_bf16.h>
#include <cstddef>

// Problem constants
#define B_ROWS 16384
#define SDIM 512
#define ADIM 64
#define KDIM 576    // SDIM + ADIM = 9 K-tiles of 64 (exact)
#define HID 1024
#define NQ 64
#define NT1 9
#define NT2 16

// prep: transposes + qoff
#define T1_BLOCKS ((KDIM / 32) * (HID / 32))   // 576
#define T2_BLOCKS ((HID / 32) * (HID / 32))    // 1024
#define PREP_BLOCKS (T1_BLOCKS + T2_BLOCKS + 1)

#define FK_LDS (16384 + 131072)   // A double-buffer (2x8KB) + B1/h1 region (128KB)

typedef __attribute__((ext_vector_type(8))) __bf16 bf16x8;
typedef __attribute__((ext_vector_type(4))) float f32x4;

static __device__ __forceinline__ float bf2f(unsigned short u) {
  union { unsigned int i; float f; } x; x.i = ((unsigned int)u) << 16; return x.f;
}
static __device__ __forceinline__ unsigned short f2bf(float f) {
  union { float f; unsigned int i; } x; x.f = f;
  unsigned int i = x.i + (0x7fffu + ((x.i >> 16) & 1u)); // RNE
  return (unsigned short)(i >> 16);
}

static __device__ __forceinline__ void gload_lds16(const unsigned short* g, unsigned short* l) {
  __builtin_amdgcn_global_load_lds(
      (const __attribute__((address_space(1))) void*)(const void*)g,
      (__attribute__((address_space(3))) void*)(void*)l, 16, 0, 0);
}

// pack 8 f32 -> 8 bf16 (RNE) in one uint4
static __device__ __forceinline__ uint4 pack8(float4 a, float4 b) {
  uint4 o;
  o.x = (unsigned)f2bf(a.x) | ((unsigned)f2bf(a.y) << 16);
  o.y = (unsigned)f2bf(a.z) | ((unsigned)f2bf(a.w) << 16);
  o.z = (unsigned)f2bf(b.x) | ((unsigned)f2bf(b.y) << 16);
  o.w = (unsigned)f2bf(b.z) | ((unsigned)f2bf(b.w) << 16);
  return o;
}

// ---- transpose helper: W [Kin][N] f32 -> Wb [N][Kin] bf16 ----
static __device__ __forceinline__ void transpose_body(
    const float* __restrict__ W, unsigned short* __restrict__ Wb,
    int Kin, int N, int k0, int n0, unsigned short* tile) {
  const int tx = threadIdx.x & 31, ty = threadIdx.x >> 5;
#pragma unroll
  for (int i = 0; i < 32; i += 8)
    tile[(ty + i) * 33 + tx] = f2bf(W[(size_t)(k0 + ty + i) * N + n0 + tx]);
  __syncthreads();
#pragma unroll
  for (int i = 0; i < 32; i += 8)
    Wb[(size_t)(n0 + ty + i) * Kin + k0 + tx] = tile[tx * 33 + ty + i];
}

// ---- prep: weight transposes + qoff ----
__global__ __launch_bounds__(256) void prep_k(
    const float* __restrict__ W1, const float* __restrict__ W2,
    const float* __restrict__ Wq1, const float* __restrict__ bq1,
    const float* __restrict__ Wq2, const float* __restrict__ bq2,
    const float* __restrict__ Wh, const float* __restrict__ bh,
    unsigned short* __restrict__ w1b, unsigned short* __restrict__ w2b,
    float* __restrict__ qoff) {
  __shared__ unsigned short tile[32 * 33];
  const int b = blockIdx.x;
  if (b < T1_BLOCKS) {
    transpose_body(W1, w1b, KDIM, HID, (b / 32) * 32, (b % 32) * 32, tile);
  } else if (b < T1_BLOCKS + T2_BLOCKS) {
    const int t = b - T1_BLOCKS;
    transpose_body(W2, w2b, HID, HID, (t / 32) * 32, (t % 32) * 32, tile);
  } else {
    const int q = threadIdx.x;
    if (q < NQ) {
      const float tau = ((float)q + 0.5f) * (1.0f / (float)NQ);
      float t1[64];
#pragma unroll
      for (int k = 0; k < 64; ++k) t1[k] = fmaxf(fmaf(tau, Wq1[k], bq1[k]), 0.f);
      float acc = bh[0];
#pragma unroll 1
      for (int j = 0; j < 64; ++j) {
        float t2 = bq2[j];
#pragma unroll
        for (int k = 0; k < 64; ++k) t2 = fmaf(t1[k], Wq2[k * 64 + j], t2);
        acc = fmaf(t2, Wh[HID + j], acc);
      }
      qoff[q] = acc;
    }
  }
}

// ---- w2c permute: w2b [N][K] -> fragment-contiguous layout ----
// frag chunk idx c = ((w*NT2 + t)*2 + kk)*8 + ni ; chunk = 64 lanes x 16B.
// lane l's 16B = w2b[w*128 + ni*16 + (l&15)][t*64 + kk*32 + (l>>4)*8 .. +7]
__global__ __launch_bounds__(256) void w2perm_k(
    const unsigned short* __restrict__ w2b, unsigned short* __restrict__ w2c) {
  const int gt = blockIdx.x * 256 + threadIdx.x;   // 131072 threads
  const int c = gt >> 6, l = gt & 63;
  const int ni = c & 7, kk = (c >> 3) & 1, t = (c >> 4) & 15, w = c >> 8;
  const int row = w * 128 + ni * 16 + (l & 15);
  const int kcol = t * 64 + kk * 32 + ((l >> 4) << 3);
  *(uint4*)(w2c + (size_t)gt * 8) = *(const uint4*)(w2b + (size_t)row * HID + kcol);
}

// ============================================================================
// WHOLE-NETWORK single kernel (r16-measured skeleton, 79.4 us).
// Round-17 change: h1 region swizzle upgraded 1-bit -> FULL 3-BIT (r3-proven
// 0-conflict formulas). Writer stores its 16B at slot (l&7)^(row&7); AF2
// reads slot j^(l&7) (j = (l>>4)|(kk<<2)). Correspondence: reader row&7 ==
// l&7 -> reads writer's col-slot j exactly. Kills the 8-way conflict on all
// 128 AF2 reads/wave that r16's (row&4) 1-bit XOR left (9.9M conflict cyc).
// Everything else byte-identical to r16.
// ============================================================================
__global__ __launch_bounds__(512, 2) void fused_all_k(
    const float* __restrict__ Xs, const float* __restrict__ Xa,
    const unsigned short* __restrict__ B1t,  // w1b [1024][576]
    const unsigned short* __restrict__ w2c,  // frag-contiguous W2 (2MB)
    const float* __restrict__ b1, const float* __restrict__ g1,
    const float* __restrict__ be1,
    const float* __restrict__ b2, const float* __restrict__ g2,
    const float* __restrict__ be2,
    const float* __restrict__ Wh, const float* __restrict__ qoff,
    float* __restrict__ Qout) {
  extern __shared__ unsigned short sm[];
  __shared__ float part[8][64][2];
  __shared__ float murs[64][2];
  __shared__ float dotf[64];
  __shared__ float qof[64];

  const int tid = threadIdx.x;
  const int w = tid >> 6, l = tid & 63;
  const int r0 = (int)blockIdx.x * 64;
  const int sb = (int)blockIdx.x % NT1;     // phase-1 K stagger

  const int sce = ((((l & 7) << 4) ^ (((l >> 3) & 4) << 3)) >> 1);
  const int lr = (l & 15) << 7;
  const int cSw = (((l >> 4) << 4) ^ ((l & 4) << 3));
  // 3-bit swizzled slot bytes for h1-region reads (r3-verified formulas)
  const int sl20 = (((l >> 4) ^ (l & 7)) << 4);
  const int sl21 = ((((l >> 4) | 4) ^ (l & 7)) << 4);

  f32x4 acc[4][8] = {};
  float4 ar0, ar1;

#define KT(x) ((((x) + sb) % NT1) << 6)
#define AF1(d, mi, kk) (*(const bf16x8*)(sm + (((d)*8192 + (mi)*2048 + lr + cSw + ((kk) << 6)) >> 1)))
// remapped B1 frag (r15-verified): lane owns 8 contiguous out-cols
#define BF1(ni, kk) (*(const bf16x8*)(sm + ((16384 + w*16384 + ((l & 15) * 8 + (ni)) * 128 + (((l >> 4) << 4) ^ (((ni) & 4) << 3)) + ((kk) << 6)) >> 1)))
#define ALOADX(kt) do { \
    const int row_ = r0 + w * 8 + (l >> 3); \
    if ((kt) < SDIM) { const float* p_ = Xs + (size_t)row_ * SDIM + (kt) + sce; \
      ar0 = *(const float4*)p_; ar1 = *(const float4*)(p_ + 4); } \
    else { const float* p_ = Xa + (size_t)row_ * ADIM + ((kt) - SDIM) + sce; \
      ar0 = *(const float4*)p_; ar1 = *(const float4*)(p_ + 4); } } while (0)
#define AWRX(d) (*(uint4*)(sm + (((d)*8192 + w * 1024 + l * 16) >> 1)) = pack8(ar0, ar1))
#define ISSUE_B1(kt) do { _Pragma("unroll") for (int i_ = 0; i_ < 16; ++i_) \
    gload_lds16(B1t + (size_t)(w * 128 + i_ * 8 + (l >> 3)) * KDIM + (kt) + sce, \
                sm + ((16384 + w * 16384 + i_ * 1024) >> 1)); } while (0)
// phase-2 A frag from resident h1 LDS: 3-bit swizzled slot (round-17 fix)
#define AF2(t, mi, kk) (*(const bf16x8*)(sm + ((16384 + ((t) >> 1) * 16384 + ((t) & 1) * 8192 + (mi)*2048 + lr + ((kk) ? sl21 : sl20)) >> 1)))
// phase-2 B 4-frag group load: ni = h*4+j
#define LOADB2H(dst, t, kk, h) do { _Pragma("unroll") for (int j_ = 0; j_ < 4; ++j_) \
    dst[j_] = *(const bf16x8*)(w2c + ((size_t)((((w * NT2 + (t)) * 2 + (kk)) * 8 + (h) * 4 + j_) * 64 + l) * 8)); } while (0)
#define MQ1(bsrc) do { _Pragma("unroll") for (int mi = 0; mi < 4; ++mi) \
    _Pragma("unroll") for (int ni = 0; ni < 8; ++ni) \
      acc[mi][ni] = __builtin_amdgcn_mfma_f32_16x16x32_bf16(af[mi], bsrc[ni], acc[mi][ni], 0, 0, 0); } while (0)
#define MQ2(cv, NO) do { _Pragma("unroll") for (int mi = 0; mi < 4; ++mi) \
    _Pragma("unroll") for (int j_ = 0; j_ < 4; ++j_) \
      acc[mi][(NO) + j_] = __builtin_amdgcn_mfma_f32_16x16x32_bf16(af2[mi], cv[j_], acc[mi][(NO) + j_], 0, 0, 0); } while (0)
#define BAR() __builtin_amdgcn_s_barrier()
#define WAITLGKM() asm volatile("s_waitcnt lgkmcnt(0)" ::: "memory")
#define WAITVM(n) asm volatile("s_waitcnt vmcnt(" #n ")" ::: "memory")
#define PRIO1() __builtin_amdgcn_s_setprio(1)
#define PRIO0() __builtin_amdgcn_s_setprio(0)

  // ---------------- phase 1: layer-1 GEMM (r13 XSRC skeleton) ----------------
  ALOADX(KT(0)); AWRX(0);
  ISSUE_B1(KT(0));
  ALOADX(KT(1));
  WAITLGKM(); BAR();

  for (int t = 0; t < NT1; ++t) {
    const int d = t & 1;
    if (t + 1 < NT1) { WAITVM(2); } else { WAITVM(0); }
    bf16x8 af[4], bfr[8];
#pragma unroll
    for (int mi = 0; mi < 4; ++mi) af[mi] = AF1(d, mi, 0);
#pragma unroll
    for (int ni = 0; ni < 8; ++ni) bfr[ni] = BF1(ni, 0);
    PRIO1(); MQ1(bfr); PRIO0();
#pragma unroll
    for (int mi = 0; mi < 4; ++mi) af[mi] = AF1(d, mi, 1);
#pragma unroll
    for (int ni = 0; ni < 8; ++ni) bfr[ni] = BF1(ni, 1);
    WAITLGKM();
    if (t + 1 < NT1) ISSUE_B1(KT(t + 1));
    if (t + 1 < NT1) AWRX((t + 1) & 1);
    PRIO1(); MQ1(bfr); PRIO0();
    if (t + 1 < NT1) { WAITLGKM(); }
    BAR();
    if (t + 2 < NT1) ALOADX(KT(t + 2));
  }

  // ---------------- epilogue 1: LN1+ReLU -> h1 into LDS ----------------
  float bcol[8], gcol[8], becol[8];
  const int cb = w * 128 + (l & 15) * 8;   // 8 contiguous cols (remap)
  *(float4*)&bcol[0]  = *(const float4*)(b1 + cb);
  *(float4*)&bcol[4]  = *(const float4*)(b1 + cb + 4);
  *(float4*)&gcol[0]  = *(const float4*)(g1 + cb);
  *(float4*)&gcol[4]  = *(const float4*)(g1 + cb + 4);
  *(float4*)&becol[0] = *(const float4*)(be1 + cb);
  *(float4*)&becol[4] = *(const float4*)(be1 + cb + 4);
#pragma unroll
  for (int mi = 0; mi < 4; ++mi)
#pragma unroll
    for (int rr = 0; rr < 4; ++rr) {
      float s1 = 0.f, s2 = 0.f;
#pragma unroll
      for (int ni = 0; ni < 8; ++ni) {
        const float x = acc[mi][ni][rr] + bcol[ni];
        s1 += x; s2 += x * x;
      }
#pragma unroll
      for (int o = 1; o < 16; o <<= 1) {
        s1 += __shfl_xor(s1, o, 64);
        s2 += __shfl_xor(s2, o, 64);
      }
      if ((l & 15) == 0) {
        const int row = mi * 16 + (l >> 4) * 4 + rr;
        part[w][row][0] = s1;
        part[w][row][1] = s2;
      }
    }
  __syncthreads();
  if (tid < 64) {
    float s1 = 0.f, s2 = 0.f;
#pragma unroll
    for (int ww = 0; ww < 8; ++ww) { s1 += part[ww][tid][0]; s2 += part[ww][tid][1]; }
    const float mu = s1 * (1.0f / HID);
    murs[tid][0] = mu;
    murs[tid][1] = rsqrtf(s2 * (1.0f / HID) - mu * mu + 1e-5f);
    qof[tid] = qoff[tid];
  }
  __syncthreads();
  // h1 write: wave-private chunk, A-frag layout, 3-bit swizzled slot
#pragma unroll
  for (int mi = 0; mi < 4; ++mi)
#pragma unroll
    for (int rr = 0; rr < 4; ++rr) {
      const int row = mi * 16 + (l >> 4) * 4 + rr;
      const float mu = murs[row][0], rs = murs[row][1];
      uint4 ov;
      unsigned int* op = (unsigned int*)&ov;
#pragma unroll
      for (int i = 0; i < 4; ++i) {
        const float y0 = fmaxf((acc[mi][2 * i][rr] + bcol[2 * i] - mu) * rs * gcol[2 * i] + becol[2 * i], 0.f);
        const float y1 = fmaxf((acc[mi][2 * i + 1][rr] + bcol[2 * i + 1] - mu) * rs * gcol[2 * i + 1] + becol[2 * i + 1], 0.f);
        op[i] = (unsigned)f2bf(y0) | ((unsigned)f2bf(y1) << 16);
      }
      *(uint4*)(sm + ((16384 + w * 16384 + ((l & 15) >> 3) * 8192 + row * 128
                       + (((l & 7) ^ (row & 7)) << 4)) >> 1)) = ov;
    }
  __syncthreads();

  // ---------------- phase 2: layer-2 GEMM, barrier-free ----------------
#pragma unroll
  for (int mi = 0; mi < 4; ++mi)
#pragma unroll
    for (int ni = 0; ni < 8; ++ni) acc[mi][ni] = (f32x4){0.f, 0.f, 0.f, 0.f};

  {
    bf16x8 ca[4], cbf[4], af2[4];
    LOADB2H(ca, 0, 0, 0);
    for (int t = 0; t < NT2; ++t) {
#pragma unroll
      for (int mi = 0; mi < 4; ++mi) af2[mi] = AF2(t, mi, 0);
      LOADB2H(cbf, t, 0, 1);
      PRIO1(); MQ2(ca, 0); PRIO0();
      LOADB2H(ca, t, 1, 0);
      PRIO1(); MQ2(cbf, 4); PRIO0();
#pragma unroll
      for (int mi = 0; mi < 4; ++mi) af2[mi] = AF2(t, mi, 1);
      LOADB2H(cbf, t, 1, 1);
      PRIO1(); MQ2(ca, 0); PRIO0();
      if (t + 1 < NT2) LOADB2H(ca, t + 1, 0, 0);
      PRIO1(); MQ2(cbf, 4); PRIO0();
    }
  }

  // ---------------- epilogue 2: LN2+ReLU + Wf-dot + qoff (r13 FINAL) -------
  float b2c[8], g2c[8], be2c[8], wf[8];
#pragma unroll
  for (int ni = 0; ni < 8; ++ni) {
    const int col = w * 128 + ni * 16 + (l & 15);
    b2c[ni] = b2[col];
    g2c[ni] = g2[col];
    be2c[ni] = be2[col];
    wf[ni] = Wh[col];
  }
#pragma unroll
  for (int mi = 0; mi < 4; ++mi)
#pragma unroll
    for (int rr = 0; rr < 4; ++rr) {
      float s1 = 0.f, s2 = 0.f;
#pragma unroll
      for (int ni = 0; ni < 8; ++ni) {
        const float x = acc[mi][ni][rr] + b2c[ni];
        s1 += x; s2 += x * x;
      }
#pragma unroll
      for (int o = 1; o < 16; o <<= 1) {
        s1 += __shfl_xor(s1, o, 64);
        s2 += __shfl_xor(s2, o, 64);
      }
      if ((l & 15) == 0) {
        const int row = mi * 16 + (l >> 4) * 4 + rr;
        part[w][row][0] = s1;
        part[w][row][1] = s2;
      }
    }
  __syncthreads();
  if (tid < 64) {
    float s1 = 0.f, s2 = 0.f;
#pragma unroll
    for (int ww = 0; ww < 8; ++ww) { s1 += part[ww][tid][0]; s2 += part[ww][tid][1]; }
    const float mu = s1 * (1.0f / HID);
    murs[tid][0] = mu;
    murs[tid][1] = rsqrtf(s2 * (1.0f / HID) - mu * mu + 1e-5f);
  }
  __syncthreads();
#pragma unroll
  for (int mi = 0; mi < 4; ++mi)
#pragma unroll
    for (int rr = 0; rr < 4; ++rr) {
      const int row = mi * 16 + (l >> 4) * 4 + rr;
      const float mu = murs[row][0], rs = murs[row][1];
      float dp = 0.f;
#pragma unroll
      for (int ni = 0; ni < 8; ++ni) {
        const float x = acc[mi][ni][rr] + b2c[ni];
        dp += fmaxf((x - mu) * rs * g2c[ni] + be2c[ni], 0.f) * wf[ni];
      }
#pragma unroll
      for (int o = 1; o < 16; o <<= 1) dp += __shfl_xor(dp, o, 64);
      if ((l & 15) == 0) part[w][row][0] = dp;
    }
  __syncthreads();
  if (tid < 64) {
    float dsum = 0.f;
#pragma unroll
    for (int ww = 0; ww < 8; ++ww) dsum += part[ww][tid][0];
    dotf[tid] = dsum;
  }
  __syncthreads();
#pragma unroll
  for (int it = 0; it < 8; ++it) {
    const int idx = tid + it * 512;
    const int row = idx >> 6, q = idx & 63;
    Qout[(size_t)(r0 + row) * NQ + q] = dotf[row] + qof[q];
  }
#undef KT
#undef AF1
#undef BF1
#undef ALOADX
#undef AWRX
#undef ISSUE_B1
#undef AF2
#undef LOADB2H
#undef MQ1
#undef MQ2
#undef BAR
#undef WAITLGKM
#undef WAITVM
}

extern "C" void kernel_launch(void* const* d_in, const int* in_sizes, int n_in,
                              void* d_out, int out_size, void* d_ws, size_t ws_size,
                              hipStream_t stream) {
  const float* state  = (const float*)d_in[0];
  const float* action = (const float*)d_in[1];
  const float* W1  = (const float*)d_in[2];
  const float* b1  = (const float*)d_in[3];
  const float* g1  = (const float*)d_in[4];
  const float* be1 = (const float*)d_in[5];
  const float* W2  = (const float*)d_in[6];
  const float* b2  = (const float*)d_in[7];
  const float* g2  = (const float*)d_in[8];
  const float* be2 = (const float*)d_in[9];
  const float* Wq1 = (const float*)d_in[10];
  const float* bq1 = (const float*)d_in[11];
  const float* Wq2 = (const float*)d_in[12];
  const float* bq2 = (const float*)d_in[13];
  const float* Wh  = (const float*)d_in[14];
  const float* bh  = (const float*)d_in[15];
  float* out = (float*)d_out;

  // workspace (~5.3 MB)
  char* ws = (char*)d_ws;
  size_t off = 0;
  float* qoff = (float*)(ws + off); off += 256;
  unsigned short* w1b = (unsigned short*)(ws + off); off += (size_t)HID * KDIM * 2;  // 1.18 MB
  unsigned short* w2b = (unsigned short*)(ws + off); off += (size_t)HID * HID * 2;   // 2.10 MB
  unsigned short* w2c = (unsigned short*)(ws + off);                                 // 2.00 MB

  (void)hipFuncSetAttribute((const void*)fused_all_k,
                            hipFuncAttributeMaxDynamicSharedMemorySize, FK_LDS);

  prep_k<<<PREP_BLOCKS, 256, 0, stream>>>(W1, W2, Wq1, bq1, Wq2, bq2, Wh, bh,
                                          w1b, w2b, qoff);
  w2perm_k<<<512, 256, 0, stream>>>(w2b, w2c);

  fused_all_k<<<B_ROWS / 64, 512, FK_LDS, stream>>>(
      state, action, w1b, w2c, b1, g1, be1, b2, g2, be2, Wh, qoff, out);
}

// Round 18
// 103.783 us; speedup vs baseline: 1.4476x; 1.0296x over previous
//
#include <hip/hip_runtime.h>
#include <hip/hip_bf16.h>
#include <cstddef>

// Problem constants
#define B_ROWS 16384
#define SDIM 512
#define ADIM 64
#define KDIM 576    // SDIM + ADIM = 9 K-tiles of 64 (exact)
#define HID 1024
#define NQ 64
#define NT1 9
#define NT2 16

// prep: W1 transpose + direct-w2c + qoff, ONE dispatch
#define T1_BLOCKS ((KDIM / 32) * (HID / 32))   // 576
#define W2C_BLOCKS 512                          // 131072 lanes / 256
#define PREP_BLOCKS (T1_BLOCKS + W2C_BLOCKS + 1)

#define FK_LDS (16384 + 131072)   // A double-buffer (2x8KB) + B1/h1 region (128KB)

typedef __attribute__((ext_vector_type(8))) __bf16 bf16x8;
typedef __attribute__((ext_vector_type(4))) float f32x4;

static __device__ __forceinline__ float bf2f(unsigned short u) {
  union { unsigned int i; float f; } x; x.i = ((unsigned int)u) << 16; return x.f;
}
static __device__ __forceinline__ unsigned short f2bf(float f) {
  union { float f; unsigned int i; } x; x.f = f;
  unsigned int i = x.i + (0x7fffu + ((x.i >> 16) & 1u)); // RNE
  return (unsigned short)(i >> 16);
}

static __device__ __forceinline__ void gload_lds16(const unsigned short* g, unsigned short* l) {
  __builtin_amdgcn_global_load_lds(
      (const __attribute__((address_space(1))) void*)(const void*)g,
      (__attribute__((address_space(3))) void*)(void*)l, 16, 0, 0);
}

// pack 8 f32 -> 8 bf16 (RNE) in one uint4
static __device__ __forceinline__ uint4 pack8(float4 a, float4 b) {
  uint4 o;
  o.x = (unsigned)f2bf(a.x) | ((unsigned)f2bf(a.y) << 16);
  o.y = (unsigned)f2bf(a.z) | ((unsigned)f2bf(a.w) << 16);
  o.z = (unsigned)f2bf(b.x) | ((unsigned)f2bf(b.y) << 16);
  o.w = (unsigned)f2bf(b.z) | ((unsigned)f2bf(b.w) << 16);
  return o;
}

// ---- prep (single dispatch): W1 transpose + direct w2c + qoff ----
// w2c direct formula (== transpose(W2) then fragment-permute, verified):
//   chunk c: ni=c&7, kk=(c>>3)&1, t=(c>>4)&15, w=c>>8
//   lane l: row = w*128+ni*16+(l&15); kcol = t*64+kk*32+((l>>4)<<3)
//   w2c[(c*64+l)*8 + j] = bf16(W2[(kcol+j)*HID + row])
__global__ __launch_bounds__(256) void prep_k(
    const float* __restrict__ W1, const float* __restrict__ W2,
    const float* __restrict__ Wq1, const float* __restrict__ bq1,
    const float* __restrict__ Wq2, const float* __restrict__ bq2,
    const float* __restrict__ Wh, const float* __restrict__ bh,
    unsigned short* __restrict__ w1b, unsigned short* __restrict__ w2c,
    float* __restrict__ qoff) {
  __shared__ unsigned short tile[32 * 33];
  const int b = blockIdx.x;
  if (b < T1_BLOCKS) {
    // W1 [KDIM][HID] f32 -> w1b [HID][KDIM] bf16
    const int k0 = (b / 32) * 32, n0 = (b % 32) * 32;
    const int tx = threadIdx.x & 31, ty = threadIdx.x >> 5;
#pragma unroll
    for (int i = 0; i < 32; i += 8)
      tile[(ty + i) * 33 + tx] = f2bf(W1[(size_t)(k0 + ty + i) * HID + n0 + tx]);
    __syncthreads();
#pragma unroll
    for (int i = 0; i < 32; i += 8)
      w1b[(size_t)(n0 + ty + i) * KDIM + k0 + tx] = tile[tx * 33 + ty + i];
  } else if (b < T1_BLOCKS + W2C_BLOCKS) {
    const int gt = (b - T1_BLOCKS) * 256 + (int)threadIdx.x;  // 0..131071
    const int c = gt >> 6, l = gt & 63;
    const int ni = c & 7, kk = (c >> 3) & 1, t = (c >> 4) & 15, w = c >> 8;
    const int row = w * 128 + ni * 16 + (l & 15);
    const int kcol = t * 64 + kk * 32 + ((l >> 4) << 3);
    uint4 ov;
    unsigned int* op = (unsigned int*)&ov;
#pragma unroll
    for (int i = 0; i < 4; ++i) {
      const float x0 = W2[(size_t)(kcol + 2 * i) * HID + row];
      const float x1 = W2[(size_t)(kcol + 2 * i + 1) * HID + row];
      op[i] = (unsigned)f2bf(x0) | ((unsigned)f2bf(x1) << 16);
    }
    *(uint4*)(w2c + (size_t)gt * 8) = ov;
  } else {
    const int q = threadIdx.x;
    if (q < NQ) {
      const float tau = ((float)q + 0.5f) * (1.0f / (float)NQ);
      float t1[64];
#pragma unroll
      for (int k = 0; k < 64; ++k) t1[k] = fmaxf(fmaf(tau, Wq1[k], bq1[k]), 0.f);
      float acc = bh[0];
#pragma unroll 1
      for (int j = 0; j < 64; ++j) {
        float t2 = bq2[j];
#pragma unroll
        for (int k = 0; k < 64; ++k) t2 = fmaf(t1[k], Wq2[k * 64 + j], t2);
        acc = fmaf(t2, Wh[HID + j], acc);
      }
      qoff[q] = acc;
    }
  }
}

// ============================================================================
// WHOLE-NETWORK single kernel — byte-identical to the r17-measured build
// (79.3 us, absmax 7.8e-3). Phase 1: layer-1 GEMM (r13 XSRC skeleton,
// r15-remapped B1 frags); epilogue 1 writes LN1+ReLU h1 into LDS (3-bit
// swizzle); phase 2: barrier-free layer-2 GEMM (A from resident LDS, W2
// streamed from fragment-contiguous w2c); epilogue 2: LN2+ReLU Wf-dot+qoff.
// ============================================================================
__global__ __launch_bounds__(512, 2) void fused_all_k(
    const float* __restrict__ Xs, const float* __restrict__ Xa,
    const unsigned short* __restrict__ B1t,  // w1b [1024][576]
    const unsigned short* __restrict__ w2c,  // frag-contiguous W2 (2MB)
    const float* __restrict__ b1, const float* __restrict__ g1,
    const float* __restrict__ be1,
    const float* __restrict__ b2, const float* __restrict__ g2,
    const float* __restrict__ be2,
    const float* __restrict__ Wh, const float* __restrict__ qoff,
    float* __restrict__ Qout) {
  extern __shared__ unsigned short sm[];
  __shared__ float part[8][64][2];
  __shared__ float murs[64][2];
  __shared__ float dotf[64];
  __shared__ float qof[64];

  const int tid = threadIdx.x;
  const int w = tid >> 6, l = tid & 63;
  const int r0 = (int)blockIdx.x * 64;
  const int sb = (int)blockIdx.x % NT1;     // phase-1 K stagger

  const int sce = ((((l & 7) << 4) ^ (((l >> 3) & 4) << 3)) >> 1);
  const int lr = (l & 15) << 7;
  const int cSw = (((l >> 4) << 4) ^ ((l & 4) << 3));
  // 3-bit swizzled slot bytes for h1-region reads
  const int sl20 = (((l >> 4) ^ (l & 7)) << 4);
  const int sl21 = ((((l >> 4) | 4) ^ (l & 7)) << 4);

  f32x4 acc[4][8] = {};
  float4 ar0, ar1;

#define KT(x) ((((x) + sb) % NT1) << 6)
#define AF1(d, mi, kk) (*(const bf16x8*)(sm + (((d)*8192 + (mi)*2048 + lr + cSw + ((kk) << 6)) >> 1)))
#define BF1(ni, kk) (*(const bf16x8*)(sm + ((16384 + w*16384 + ((l & 15) * 8 + (ni)) * 128 + (((l >> 4) << 4) ^ (((ni) & 4) << 3)) + ((kk) << 6)) >> 1)))
#define ALOADX(kt) do { \
    const int row_ = r0 + w * 8 + (l >> 3); \
    if ((kt) < SDIM) { const float* p_ = Xs + (size_t)row_ * SDIM + (kt) + sce; \
      ar0 = *(const float4*)p_; ar1 = *(const float4*)(p_ + 4); } \
    else { const float* p_ = Xa + (size_t)row_ * ADIM + ((kt) - SDIM) + sce; \
      ar0 = *(const float4*)p_; ar1 = *(const float4*)(p_ + 4); } } while (0)
#define AWRX(d) (*(uint4*)(sm + (((d)*8192 + w * 1024 + l * 16) >> 1)) = pack8(ar0, ar1))
#define ISSUE_B1(kt) do { _Pragma("unroll") for (int i_ = 0; i_ < 16; ++i_) \
    gload_lds16(B1t + (size_t)(w * 128 + i_ * 8 + (l >> 3)) * KDIM + (kt) + sce, \
                sm + ((16384 + w * 16384 + i_ * 1024) >> 1)); } while (0)
#define AF2(t, mi, kk) (*(const bf16x8*)(sm + ((16384 + ((t) >> 1) * 16384 + ((t) & 1) * 8192 + (mi)*2048 + lr + ((kk) ? sl21 : sl20)) >> 1)))
#define LOADB2H(dst, t, kk, h) do { _Pragma("unroll") for (int j_ = 0; j_ < 4; ++j_) \
    dst[j_] = *(const bf16x8*)(w2c + ((size_t)((((w * NT2 + (t)) * 2 + (kk)) * 8 + (h) * 4 + j_) * 64 + l) * 8)); } while (0)
#define MQ1(bsrc) do { _Pragma("unroll") for (int mi = 0; mi < 4; ++mi) \
    _Pragma("unroll") for (int ni = 0; ni < 8; ++ni) \
      acc[mi][ni] = __builtin_amdgcn_mfma_f32_16x16x32_bf16(af[mi], bsrc[ni], acc[mi][ni], 0, 0, 0); } while (0)
#define MQ2(cv, NO) do { _Pragma("unroll") for (int mi = 0; mi < 4; ++mi) \
    _Pragma("unroll") for (int j_ = 0; j_ < 4; ++j_) \
      acc[mi][(NO) + j_] = __builtin_amdgcn_mfma_f32_16x16x32_bf16(af2[mi], cv[j_], acc[mi][(NO) + j_], 0, 0, 0); } while (0)
#define BAR() __builtin_amdgcn_s_barrier()
#define WAITLGKM() asm volatile("s_waitcnt lgkmcnt(0)" ::: "memory")
#define WAITVM(n) asm volatile("s_waitcnt vmcnt(" #n ")" ::: "memory")
#define PRIO1() __builtin_amdgcn_s_setprio(1)
#define PRIO0() __builtin_amdgcn_s_setprio(0)

  // ---------------- phase 1: layer-1 GEMM ----------------
  ALOADX(KT(0)); AWRX(0);
  ISSUE_B1(KT(0));
  ALOADX(KT(1));
  WAITLGKM(); BAR();

  for (int t = 0; t < NT1; ++t) {
    const int d = t & 1;
    if (t + 1 < NT1) { WAITVM(2); } else { WAITVM(0); }
    bf16x8 af[4], bfr[8];
#pragma unroll
    for (int mi = 0; mi < 4; ++mi) af[mi] = AF1(d, mi, 0);
#pragma unroll
    for (int ni = 0; ni < 8; ++ni) bfr[ni] = BF1(ni, 0);
    PRIO1(); MQ1(bfr); PRIO0();
#pragma unroll
    for (int mi = 0; mi < 4; ++mi) af[mi] = AF1(d, mi, 1);
#pragma unroll
    for (int ni = 0; ni < 8; ++ni) bfr[ni] = BF1(ni, 1);
    WAITLGKM();
    if (t + 1 < NT1) ISSUE_B1(KT(t + 1));
    if (t + 1 < NT1) AWRX((t + 1) & 1);
    PRIO1(); MQ1(bfr); PRIO0();
    if (t + 1 < NT1) { WAITLGKM(); }
    BAR();
    if (t + 2 < NT1) ALOADX(KT(t + 2));
  }

  // ---------------- epilogue 1: LN1+ReLU -> h1 into LDS ----------------
  float bcol[8], gcol[8], becol[8];
  const int cb = w * 128 + (l & 15) * 8;
  *(float4*)&bcol[0]  = *(const float4*)(b1 + cb);
  *(float4*)&bcol[4]  = *(const float4*)(b1 + cb + 4);
  *(float4*)&gcol[0]  = *(const float4*)(g1 + cb);
  *(float4*)&gcol[4]  = *(const float4*)(g1 + cb + 4);
  *(float4*)&becol[0] = *(const float4*)(be1 + cb);
  *(float4*)&becol[4] = *(const float4*)(be1 + cb + 4);
#pragma unroll
  for (int mi = 0; mi < 4; ++mi)
#pragma unroll
    for (int rr = 0; rr < 4; ++rr) {
      float s1 = 0.f, s2 = 0.f;
#pragma unroll
      for (int ni = 0; ni < 8; ++ni) {
        const float x = acc[mi][ni][rr] + bcol[ni];
        s1 += x; s2 += x * x;
      }
#pragma unroll
      for (int o = 1; o < 16; o <<= 1) {
        s1 += __shfl_xor(s1, o, 64);
        s2 += __shfl_xor(s2, o, 64);
      }
      if ((l & 15) == 0) {
        const int row = mi * 16 + (l >> 4) * 4 + rr;
        part[w][row][0] = s1;
        part[w][row][1] = s2;
      }
    }
  __syncthreads();
  if (tid < 64) {
    float s1 = 0.f, s2 = 0.f;
#pragma unroll
    for (int ww = 0; ww < 8; ++ww) { s1 += part[ww][tid][0]; s2 += part[ww][tid][1]; }
    const float mu = s1 * (1.0f / HID);
    murs[tid][0] = mu;
    murs[tid][1] = rsqrtf(s2 * (1.0f / HID) - mu * mu + 1e-5f);
    qof[tid] = qoff[tid];
  }
  __syncthreads();
#pragma unroll
  for (int mi = 0; mi < 4; ++mi)
#pragma unroll
    for (int rr = 0; rr < 4; ++rr) {
      const int row = mi * 16 + (l >> 4) * 4 + rr;
      const float mu = murs[row][0], rs = murs[row][1];
      uint4 ov;
      unsigned int* op = (unsigned int*)&ov;
#pragma unroll
      for (int i = 0; i < 4; ++i) {
        const float y0 = fmaxf((acc[mi][2 * i][rr] + bcol[2 * i] - mu) * rs * gcol[2 * i] + becol[2 * i], 0.f);
        const float y1 = fmaxf((acc[mi][2 * i + 1][rr] + bcol[2 * i + 1] - mu) * rs * gcol[2 * i + 1] + becol[2 * i + 1], 0.f);
        op[i] = (unsigned)f2bf(y0) | ((unsigned)f2bf(y1) << 16);
      }
      *(uint4*)(sm + ((16384 + w * 16384 + ((l & 15) >> 3) * 8192 + row * 128
                       + (((l & 7) ^ (row & 7)) << 4)) >> 1)) = ov;
    }
  __syncthreads();

  // ---------------- phase 2: layer-2 GEMM, barrier-free ----------------
#pragma unroll
  for (int mi = 0; mi < 4; ++mi)
#pragma unroll
    for (int ni = 0; ni < 8; ++ni) acc[mi][ni] = (f32x4){0.f, 0.f, 0.f, 0.f};

  {
    bf16x8 ca[4], cbf[4], af2[4];
    LOADB2H(ca, 0, 0, 0);
    for (int t = 0; t < NT2; ++t) {
#pragma unroll
      for (int mi = 0; mi < 4; ++mi) af2[mi] = AF2(t, mi, 0);
      LOADB2H(cbf, t, 0, 1);
      PRIO1(); MQ2(ca, 0); PRIO0();
      LOADB2H(ca, t, 1, 0);
      PRIO1(); MQ2(cbf, 4); PRIO0();
#pragma unroll
      for (int mi = 0; mi < 4; ++mi) af2[mi] = AF2(t, mi, 1);
      LOADB2H(cbf, t, 1, 1);
      PRIO1(); MQ2(ca, 0); PRIO0();
      if (t + 1 < NT2) LOADB2H(ca, t + 1, 0, 0);
      PRIO1(); MQ2(cbf, 4); PRIO0();
    }
  }

  // ---------------- epilogue 2: LN2+ReLU + Wf-dot + qoff ----------------
  float b2c[8], g2c[8], be2c[8], wf[8];
#pragma unroll
  for (int ni = 0; ni < 8; ++ni) {
    const int col = w * 128 + ni * 16 + (l & 15);
    b2c[ni] = b2[col];
    g2c[ni] = g2[col];
    be2c[ni] = be2[col];
    wf[ni] = Wh[col];
  }
#pragma unroll
  for (int mi = 0; mi < 4; ++mi)
#pragma unroll
    for (int rr = 0; rr < 4; ++rr) {
      float s1 = 0.f, s2 = 0.f;
#pragma unroll
      for (int ni = 0; ni < 8; ++ni) {
        const float x = acc[mi][ni][rr] + b2c[ni];
        s1 += x; s2 += x * x;
      }
#pragma unroll
      for (int o = 1; o < 16; o <<= 1) {
        s1 += __shfl_xor(s1, o, 64);
        s2 += __shfl_xor(s2, o, 64);
      }
      if ((l & 15) == 0) {
        const int row = mi * 16 + (l >> 4) * 4 + rr;
        part[w][row][0] = s1;
        part[w][row][1] = s2;
      }
    }
  __syncthreads();
  if (tid < 64) {
    float s1 = 0.f, s2 = 0.f;
#pragma unroll
    for (int ww = 0; ww < 8; ++ww) { s1 += part[ww][tid][0]; s2 += part[ww][tid][1]; }
    const float mu = s1 * (1.0f / HID);
    murs[tid][0] = mu;
    murs[tid][1] = rsqrtf(s2 * (1.0f / HID) - mu * mu + 1e-5f);
  }
  __syncthreads();
#pragma unroll
  for (int mi = 0; mi < 4; ++mi)
#pragma unroll
    for (int rr = 0; rr < 4; ++rr) {
      const int row = mi * 16 + (l >> 4) * 4 + rr;
      const float mu = murs[row][0], rs = murs[row][1];
      float dp = 0.f;
#pragma unroll
      for (int ni = 0; ni < 8; ++ni) {
        const float x = acc[mi][ni][rr] + b2c[ni];
        dp += fmaxf((x - mu) * rs * g2c[ni] + be2c[ni], 0.f) * wf[ni];
      }
#pragma unroll
      for (int o = 1; o < 16; o <<= 1) dp += __shfl_xor(dp, o, 64);
      if ((l & 15) == 0) part[w][row][0] = dp;
    }
  __syncthreads();
  if (tid < 64) {
    float dsum = 0.f;
#pragma unroll
    for (int ww = 0; ww < 8; ++ww) dsum += part[ww][tid][0];
    dotf[tid] = dsum;
  }
  __syncthreads();
#pragma unroll
  for (int it = 0; it < 8; ++it) {
    const int idx = tid + it * 512;
    const int row = idx >> 6, q = idx & 63;
    Qout[(size_t)(r0 + row) * NQ + q] = dotf[row] + qof[q];
  }
#undef KT
#undef AF1
#undef BF1
#undef ALOADX
#undef AWRX
#undef ISSUE_B1
#undef AF2
#undef LOADB2H
#undef MQ1
#undef MQ2
#undef BAR
#undef WAITLGKM
#undef WAITVM
}

extern "C" void kernel_launch(void* const* d_in, const int* in_sizes, int n_in,
                              void* d_out, int out_size, void* d_ws, size_t ws_size,
                              hipStream_t stream) {
  const float* state  = (const float*)d_in[0];
  const float* action = (const float*)d_in[1];
  const float* W1  = (const float*)d_in[2];
  const float* b1  = (const float*)d_in[3];
  const float* g1  = (const float*)d_in[4];
  const float* be1 = (const float*)d_in[5];
  const float* W2  = (const float*)d_in[6];
  const float* b2  = (const float*)d_in[7];
  const float* g2  = (const float*)d_in[8];
  const float* be2 = (const float*)d_in[9];
  const float* Wq1 = (const float*)d_in[10];
  const float* bq1 = (const float*)d_in[11];
  const float* Wq2 = (const float*)d_in[12];
  const float* bq2 = (const float*)d_in[13];
  const float* Wh  = (const float*)d_in[14];
  const float* bh  = (const float*)d_in[15];
  float* out = (float*)d_out;

  // workspace (~3.2 MB)
  char* ws = (char*)d_ws;
  size_t off = 0;
  float* qoff = (float*)(ws + off); off += 256;
  unsigned short* w1b = (unsigned short*)(ws + off); off += (size_t)HID * KDIM * 2;  // 1.18 MB
  unsigned short* w2c = (unsigned short*)(ws + off);                                 // 2.00 MB

  (void)hipFuncSetAttribute((const void*)fused_all_k,
                            hipFuncAttributeMaxDynamicSharedMemorySize, FK_LDS);

  prep_k<<<PREP_BLOCKS, 256, 0, stream>>>(W1, W2, Wq1, bq1, Wq2, bq2, Wh, bh,
                                          w1b, w2c, qoff);

  fused_all_k<<<B_ROWS / 64, 512, FK_LDS, stream>>>(
      state, action, w1b, w2c, b1, g1, be1, b2, g2, be2, Wh, qoff, out);
}

// Round 19
// 103.218 us; speedup vs baseline: 1.4555x; 1.0055x over previous
//
#include <hip/hip_runtime.h>
#include <hip/hip_bf16.h>
#include <cstddef>

// Problem constants
#define B_ROWS 16384
#define SDIM 512
#define ADIM 64
#define KDIM 576    // SDIM + ADIM = 9 K-tiles of 64 (exact)
#define HID 1024
#define NQ 64
#define NT1 9
#define NT2 16

// prep: W1 transpose + coalesced-w2c + qoff, ONE dispatch
#define T1_BLOCKS ((KDIM / 32) * (HID / 32))   // 576
#define W2C_BLOCKS 512                          // 1024 32x32 tiles, 2 per block
#define PREP_BLOCKS (T1_BLOCKS + W2C_BLOCKS + 1)

#define FK_LDS (16384 + 131072)   // A double-buffer (2x8KB) + B1/h1 region (128KB)

typedef __attribute__((ext_vector_type(8))) __bf16 bf16x8;
typedef __attribute__((ext_vector_type(4))) float f32x4;

static __device__ __forceinline__ float bf2f(unsigned short u) {
  union { unsigned int i; float f; } x; x.i = ((unsigned int)u) << 16; return x.f;
}
static __device__ __forceinline__ unsigned short f2bf(float f) {
  union { float f; unsigned int i; } x; x.f = f;
  unsigned int i = x.i + (0x7fffu + ((x.i >> 16) & 1u)); // RNE
  return (unsigned short)(i >> 16);
}

static __device__ __forceinline__ void gload_lds16(const unsigned short* g, unsigned short* l) {
  __builtin_amdgcn_global_load_lds(
      (const __attribute__((address_space(1))) void*)(const void*)g,
      (__attribute__((address_space(3))) void*)(void*)l, 16, 0, 0);
}

// pack 8 f32 -> 8 bf16 (RNE) in one uint4
static __device__ __forceinline__ uint4 pack8(float4 a, float4 b) {
  uint4 o;
  o.x = (unsigned)f2bf(a.x) | ((unsigned)f2bf(a.y) << 16);
  o.y = (unsigned)f2bf(a.z) | ((unsigned)f2bf(a.w) << 16);
  o.z = (unsigned)f2bf(b.x) | ((unsigned)f2bf(b.y) << 16);
  o.w = (unsigned)f2bf(b.z) | ((unsigned)f2bf(b.w) << 16);
  return o;
}

// ---- prep (single dispatch): W1 transpose + coalesced w2c + qoff ----
// w2c mapping (r18-verified): for output neuron r and k-base k (k%8==0):
//   w=r>>7, ni=(r>>4)&7, lan_lo=r&15; t=k>>6, kk=(k>>5)&1, l_hi=(k>>3)&3;
//   chunk=((w*16+t)*2+kk)*8+ni; lane=l_hi*16+lan_lo;
//   w2c[(chunk*64+lane)*8 + j] = bf16(W2[(k+j)*HID + r]), j=0..7.
// Round-19: produce this via LDS 32x32 transpose tiles (coalesced W2 reads;
// r18's direct path did 8 scattered 64B gathers/thread -> ~15us dispatch).
__global__ __launch_bounds__(256) void prep_k(
    const float* __restrict__ W1, const float* __restrict__ W2,
    const float* __restrict__ Wq1, const float* __restrict__ bq1,
    const float* __restrict__ Wq2, const float* __restrict__ bq2,
    const float* __restrict__ Wh, const float* __restrict__ bh,
    unsigned short* __restrict__ w1b, unsigned short* __restrict__ w2c,
    float* __restrict__ qoff) {
  __shared__ unsigned short tile[2 * 32 * 33];
  const int b = blockIdx.x;
  if (b < T1_BLOCKS) {
    // W1 [KDIM][HID] f32 -> w1b [HID][KDIM] bf16
    const int k0 = (b / 32) * 32, n0 = (b % 32) * 32;
    const int tx = threadIdx.x & 31, ty = threadIdx.x >> 5;
#pragma unroll
    for (int i = 0; i < 32; i += 8)
      tile[(ty + i) * 33 + tx] = f2bf(W1[(size_t)(k0 + ty + i) * HID + n0 + tx]);
    __syncthreads();
#pragma unroll
    for (int i = 0; i < 32; i += 8)
      w1b[(size_t)(n0 + ty + i) * KDIM + k0 + tx] = tile[tx * 33 + ty + i];
  } else if (b < T1_BLOCKS + W2C_BLOCKS) {
    // two 32x32 W2 tiles per block through LDS
    const int tp = (b - T1_BLOCKS) * 2 + ((int)threadIdx.x >> 7);  // tile idx
    const int k0 = (tp & 31) * 32, r0 = (tp >> 5) * 32;
    const int tid2 = (int)threadIdx.x & 127;
    unsigned short* tl = tile + (((int)threadIdx.x >> 7) * 32 * 33);
    {
      const int rx = tid2 & 31, ky = tid2 >> 5;  // ky 0..3
#pragma unroll
      for (int i = 0; i < 8; ++i)
        tl[(ky * 8 + i) * 33 + rx] = f2bf(W2[(size_t)(k0 + ky * 8 + i) * HID + r0 + rx]);
    }
    __syncthreads();
    {
      const int r_off = tid2 & 31, s = tid2 >> 5;  // s 0..3 (k-group)
      const int r = r0 + r_off, k = k0 + s * 8;
      const int wq = r >> 7, ni = (r >> 4) & 7, lan_lo = r & 15;
      const int t = k >> 6, kk = (k >> 5) & 1, l_hi = (k >> 3) & 3;
      const int chunk = ((wq * 16 + t) * 2 + kk) * 8 + ni;
      const int lane = l_hi * 16 + lan_lo;
      uint4 ov;
      unsigned int* op = (unsigned int*)&ov;
#pragma unroll
      for (int i = 0; i < 4; ++i)
        op[i] = (unsigned)tl[(s * 8 + 2 * i) * 33 + r_off]
              | ((unsigned)tl[(s * 8 + 2 * i + 1) * 33 + r_off] << 16);
      *(uint4*)(w2c + (size_t)(chunk * 64 + lane) * 8) = ov;
    }
  } else {
    const int q = threadIdx.x;
    if (q < NQ) {
      const float tau = ((float)q + 0.5f) * (1.0f / (float)NQ);
      float t1[64];
#pragma unroll
      for (int k = 0; k < 64; ++k) t1[k] = fmaxf(fmaf(tau, Wq1[k], bq1[k]), 0.f);
      float acc = bh[0];
#pragma unroll 1
      for (int j = 0; j < 64; ++j) {
        float t2 = bq2[j];
#pragma unroll
        for (int k = 0; k < 64; ++k) t2 = fmaf(t1[k], Wq2[k * 64 + j], t2);
        acc = fmaf(t2, Wh[HID + j], acc);
      }
      qoff[q] = acc;
    }
  }
}

// ============================================================================
// WHOLE-NETWORK single kernel — byte-identical to the r17/r18-measured build
// (79 us, absmax 7.8e-3). Phase 1: layer-1 GEMM (r13 XSRC skeleton,
// r15-remapped B1 frags); epilogue 1 writes LN1+ReLU h1 into LDS (3-bit
// swizzle); phase 2: barrier-free layer-2 GEMM (A from resident LDS, W2
// streamed from fragment-contiguous w2c); epilogue 2: LN2+ReLU Wf-dot+qoff.
// ============================================================================
__global__ __launch_bounds__(512, 2) void fused_all_k(
    const float* __restrict__ Xs, const float* __restrict__ Xa,
    const unsigned short* __restrict__ B1t,  // w1b [1024][576]
    const unsigned short* __restrict__ w2c,  // frag-contiguous W2 (2MB)
    const float* __restrict__ b1, const float* __restrict__ g1,
    const float* __restrict__ be1,
    const float* __restrict__ b2, const float* __restrict__ g2,
    const float* __restrict__ be2,
    const float* __restrict__ Wh, const float* __restrict__ qoff,
    float* __restrict__ Qout) {
  extern __shared__ unsigned short sm[];
  __shared__ float part[8][64][2];
  __shared__ float murs[64][2];
  __shared__ float dotf[64];
  __shared__ float qof[64];

  const int tid = threadIdx.x;
  const int w = tid >> 6, l = tid & 63;
  const int r0 = (int)blockIdx.x * 64;
  const int sb = (int)blockIdx.x % NT1;     // phase-1 K stagger

  const int sce = ((((l & 7) << 4) ^ (((l >> 3) & 4) << 3)) >> 1);
  const int lr = (l & 15) << 7;
  const int cSw = (((l >> 4) << 4) ^ ((l & 4) << 3));
  // 3-bit swizzled slot bytes for h1-region reads
  const int sl20 = (((l >> 4) ^ (l & 7)) << 4);
  const int sl21 = ((((l >> 4) | 4) ^ (l & 7)) << 4);

  f32x4 acc[4][8] = {};
  float4 ar0, ar1;

#define KT(x) ((((x) + sb) % NT1) << 6)
#define AF1(d, mi, kk) (*(const bf16x8*)(sm + (((d)*8192 + (mi)*2048 + lr + cSw + ((kk) << 6)) >> 1)))
#define BF1(ni, kk) (*(const bf16x8*)(sm + ((16384 + w*16384 + ((l & 15) * 8 + (ni)) * 128 + (((l >> 4) << 4) ^ (((ni) & 4) << 3)) + ((kk) << 6)) >> 1)))
#define ALOADX(kt) do { \
    const int row_ = r0 + w * 8 + (l >> 3); \
    if ((kt) < SDIM) { const float* p_ = Xs + (size_t)row_ * SDIM + (kt) + sce; \
      ar0 = *(const float4*)p_; ar1 = *(const float4*)(p_ + 4); } \
    else { const float* p_ = Xa + (size_t)row_ * ADIM + ((kt) - SDIM) + sce; \
      ar0 = *(const float4*)p_; ar1 = *(const float4*)(p_ + 4); } } while (0)
#define AWRX(d) (*(uint4*)(sm + (((d)*8192 + w * 1024 + l * 16) >> 1)) = pack8(ar0, ar1))
#define ISSUE_B1(kt) do { _Pragma("unroll") for (int i_ = 0; i_ < 16; ++i_) \
    gload_lds16(B1t + (size_t)(w * 128 + i_ * 8 + (l >> 3)) * KDIM + (kt) + sce, \
                sm + ((16384 + w * 16384 + i_ * 1024) >> 1)); } while (0)
#define AF2(t, mi, kk) (*(const bf16x8*)(sm + ((16384 + ((t) >> 1) * 16384 + ((t) & 1) * 8192 + (mi)*2048 + lr + ((kk) ? sl21 : sl20)) >> 1)))
#define LOADB2H(dst, t, kk, h) do { _Pragma("unroll") for (int j_ = 0; j_ < 4; ++j_) \
    dst[j_] = *(const bf16x8*)(w2c + ((size_t)((((w * NT2 + (t)) * 2 + (kk)) * 8 + (h) * 4 + j_) * 64 + l) * 8)); } while (0)
#define MQ1(bsrc) do { _Pragma("unroll") for (int mi = 0; mi < 4; ++mi) \
    _Pragma("unroll") for (int ni = 0; ni < 8; ++ni) \
      acc[mi][ni] = __builtin_amdgcn_mfma_f32_16x16x32_bf16(af[mi], bsrc[ni], acc[mi][ni], 0, 0, 0); } while (0)
#define MQ2(cv, NO) do { _Pragma("unroll") for (int mi = 0; mi < 4; ++mi) \
    _Pragma("unroll") for (int j_ = 0; j_ < 4; ++j_) \
      acc[mi][(NO) + j_] = __builtin_amdgcn_mfma_f32_16x16x32_bf16(af2[mi], cv[j_], acc[mi][(NO) + j_], 0, 0, 0); } while (0)
#define BAR() __builtin_amdgcn_s_barrier()
#define WAITLGKM() asm volatile("s_waitcnt lgkmcnt(0)" ::: "memory")
#define WAITVM(n) asm volatile("s_waitcnt vmcnt(" #n ")" ::: "memory")
#define PRIO1() __builtin_amdgcn_s_setprio(1)
#define PRIO0() __builtin_amdgcn_s_setprio(0)

  // ---------------- phase 1: layer-1 GEMM ----------------
  ALOADX(KT(0)); AWRX(0);
  ISSUE_B1(KT(0));
  ALOADX(KT(1));
  WAITLGKM(); BAR();

  for (int t = 0; t < NT1; ++t) {
    const int d = t & 1;
    if (t + 1 < NT1) { WAITVM(2); } else { WAITVM(0); }
    bf16x8 af[4], bfr[8];
#pragma unroll
    for (int mi = 0; mi < 4; ++mi) af[mi] = AF1(d, mi, 0);
#pragma unroll
    for (int ni = 0; ni < 8; ++ni) bfr[ni] = BF1(ni, 0);
    PRIO1(); MQ1(bfr); PRIO0();
#pragma unroll
    for (int mi = 0; mi < 4; ++mi) af[mi] = AF1(d, mi, 1);
#pragma unroll
    for (int ni = 0; ni < 8; ++ni) bfr[ni] = BF1(ni, 1);
    WAITLGKM();
    if (t + 1 < NT1) ISSUE_B1(KT(t + 1));
    if (t + 1 < NT1) AWRX((t + 1) & 1);
    PRIO1(); MQ1(bfr); PRIO0();
    if (t + 1 < NT1) { WAITLGKM(); }
    BAR();
    if (t + 2 < NT1) ALOADX(KT(t + 2));
  }

  // ---------------- epilogue 1: LN1+ReLU -> h1 into LDS ----------------
  float bcol[8], gcol[8], becol[8];
  const int cb = w * 128 + (l & 15) * 8;
  *(float4*)&bcol[0]  = *(const float4*)(b1 + cb);
  *(float4*)&bcol[4]  = *(const float4*)(b1 + cb + 4);
  *(float4*)&gcol[0]  = *(const float4*)(g1 + cb);
  *(float4*)&gcol[4]  = *(const float4*)(g1 + cb + 4);
  *(float4*)&becol[0] = *(const float4*)(be1 + cb);
  *(float4*)&becol[4] = *(const float4*)(be1 + cb + 4);
#pragma unroll
  for (int mi = 0; mi < 4; ++mi)
#pragma unroll
    for (int rr = 0; rr < 4; ++rr) {
      float s1 = 0.f, s2 = 0.f;
#pragma unroll
      for (int ni = 0; ni < 8; ++ni) {
        const float x = acc[mi][ni][rr] + bcol[ni];
        s1 += x; s2 += x * x;
      }
#pragma unroll
      for (int o = 1; o < 16; o <<= 1) {
        s1 += __shfl_xor(s1, o, 64);
        s2 += __shfl_xor(s2, o, 64);
      }
      if ((l & 15) == 0) {
        const int row = mi * 16 + (l >> 4) * 4 + rr;
        part[w][row][0] = s1;
        part[w][row][1] = s2;
      }
    }
  __syncthreads();
  if (tid < 64) {
    float s1 = 0.f, s2 = 0.f;
#pragma unroll
    for (int ww = 0; ww < 8; ++ww) { s1 += part[ww][tid][0]; s2 += part[ww][tid][1]; }
    const float mu = s1 * (1.0f / HID);
    murs[tid][0] = mu;
    murs[tid][1] = rsqrtf(s2 * (1.0f / HID) - mu * mu + 1e-5f);
    qof[tid] = qoff[tid];
  }
  __syncthreads();
#pragma unroll
  for (int mi = 0; mi < 4; ++mi)
#pragma unroll
    for (int rr = 0; rr < 4; ++rr) {
      const int row = mi * 16 + (l >> 4) * 4 + rr;
      const float mu = murs[row][0], rs = murs[row][1];
      uint4 ov;
      unsigned int* op = (unsigned int*)&ov;
#pragma unroll
      for (int i = 0; i < 4; ++i) {
        const float y0 = fmaxf((acc[mi][2 * i][rr] + bcol[2 * i] - mu) * rs * gcol[2 * i] + becol[2 * i], 0.f);
        const float y1 = fmaxf((acc[mi][2 * i + 1][rr] + bcol[2 * i + 1] - mu) * rs * gcol[2 * i + 1] + becol[2 * i + 1], 0.f);
        op[i] = (unsigned)f2bf(y0) | ((unsigned)f2bf(y1) << 16);
      }
      *(uint4*)(sm + ((16384 + w * 16384 + ((l & 15) >> 3) * 8192 + row * 128
                       + (((l & 7) ^ (row & 7)) << 4)) >> 1)) = ov;
    }
  __syncthreads();

  // ---------------- phase 2: layer-2 GEMM, barrier-free ----------------
#pragma unroll
  for (int mi = 0; mi < 4; ++mi)
#pragma unroll
    for (int ni = 0; ni < 8; ++ni) acc[mi][ni] = (f32x4){0.f, 0.f, 0.f, 0.f};

  {
    bf16x8 ca[4], cbf[4], af2[4];
    LOADB2H(ca, 0, 0, 0);
    for (int t = 0; t < NT2; ++t) {
#pragma unroll
      for (int mi = 0; mi < 4; ++mi) af2[mi] = AF2(t, mi, 0);
      LOADB2H(cbf, t, 0, 1);
      PRIO1(); MQ2(ca, 0); PRIO0();
      LOADB2H(ca, t, 1, 0);
      PRIO1(); MQ2(cbf, 4); PRIO0();
#pragma unroll
      for (int mi = 0; mi < 4; ++mi) af2[mi] = AF2(t, mi, 1);
      LOADB2H(cbf, t, 1, 1);
      PRIO1(); MQ2(ca, 0); PRIO0();
      if (t + 1 < NT2) LOADB2H(ca, t + 1, 0, 0);
      PRIO1(); MQ2(cbf, 4); PRIO0();
    }
  }

  // ---------------- epilogue 2: LN2+ReLU + Wf-dot + qoff ----------------
  float b2c[8], g2c[8], be2c[8], wf[8];
#pragma unroll
  for (int ni = 0; ni < 8; ++ni) {
    const int col = w * 128 + ni * 16 + (l & 15);
    b2c[ni] = b2[col];
    g2c[ni] = g2[col];
    be2c[ni] = be2[col];
    wf[ni] = Wh[col];
  }
#pragma unroll
  for (int mi = 0; mi < 4; ++mi)
#pragma unroll
    for (int rr = 0; rr < 4; ++rr) {
      float s1 = 0.f, s2 = 0.f;
#pragma unroll
      for (int ni = 0; ni < 8; ++ni) {
        const float x = acc[mi][ni][rr] + b2c[ni];
        s1 += x; s2 += x * x;
      }
#pragma unroll
      for (int o = 1; o < 16; o <<= 1) {
        s1 += __shfl_xor(s1, o, 64);
        s2 += __shfl_xor(s2, o, 64);
      }
      if ((l & 15) == 0) {
        const int row = mi * 16 + (l >> 4) * 4 + rr;
        part[w][row][0] = s1;
        part[w][row][1] = s2;
      }
    }
  __syncthreads();
  if (tid < 64) {
    float s1 = 0.f, s2 = 0.f;
#pragma unroll
    for (int ww = 0; ww < 8; ++ww) { s1 += part[ww][tid][0]; s2 += part[ww][tid][1]; }
    const float mu = s1 * (1.0f / HID);
    murs[tid][0] = mu;
    murs[tid][1] = rsqrtf(s2 * (1.0f / HID) - mu * mu + 1e-5f);
  }
  __syncthreads();
#pragma unroll
  for (int mi = 0; mi < 4; ++mi)
#pragma unroll
    for (int rr = 0; rr < 4; ++rr) {
      const int row = mi * 16 + (l >> 4) * 4 + rr;
      const float mu = murs[row][0], rs = murs[row][1];
      float dp = 0.f;
#pragma unroll
      for (int ni = 0; ni < 8; ++ni) {
        const float x = acc[mi][ni][rr] + b2c[ni];
        dp += fmaxf((x - mu) * rs * g2c[ni] + be2c[ni], 0.f) * wf[ni];
      }
#pragma unroll
      for (int o = 1; o < 16; o <<= 1) dp += __shfl_xor(dp, o, 64);
      if ((l & 15) == 0) part[w][row][0] = dp;
    }
  __syncthreads();
  if (tid < 64) {
    float dsum = 0.f;
#pragma unroll
    for (int ww = 0; ww < 8; ++ww) dsum += part[ww][tid][0];
    dotf[tid] = dsum;
  }
  __syncthreads();
#pragma unroll
  for (int it = 0; it < 8; ++it) {
    const int idx = tid + it * 512;
    const int row = idx >> 6, q = idx & 63;
    Qout[(size_t)(r0 + row) * NQ + q] = dotf[row] + qof[q];
  }
#undef KT
#undef AF1
#undef BF1
#undef ALOADX
#undef AWRX
#undef ISSUE_B1
#undef AF2
#undef LOADB2H
#undef MQ1
#undef MQ2
#undef BAR
#undef WAITLGKM
#undef WAITVM
}

extern "C" void kernel_launch(void* const* d_in, const int* in_sizes, int n_in,
                              void* d_out, int out_size, void* d_ws, size_t ws_size,
                              hipStream_t stream) {
  const float* state  = (const float*)d_in[0];
  const float* action = (const float*)d_in[1];
  const float* W1  = (const float*)d_in[2];
  const float* b1  = (const float*)d_in[3];
  const float* g1  = (const float*)d_in[4];
  const float* be1 = (const float*)d_in[5];
  const float* W2  = (const float*)d_in[6];
  const float* b2  = (const float*)d_in[7];
  const float* g2  = (const float*)d_in[8];
  const float* be2 = (const float*)d_in[9];
  const float* Wq1 = (const float*)d_in[10];
  const float* bq1 = (const float*)d_in[11];
  const float* Wq2 = (const float*)d_in[12];
  const float* bq2 = (const float*)d_in[13];
  const float* Wh  = (const float*)d_in[14];
  const float* bh  = (const float*)d_in[15];
  float* out = (float*)d_out;

  // workspace (~3.2 MB)
  char* ws = (char*)d_ws;
  size_t off = 0;
  float* qoff = (float*)(ws + off); off += 256;
  unsigned short* w1b = (unsigned short*)(ws + off); off += (size_t)HID * KDIM * 2;  // 1.18 MB
  unsigned short* w2c = (unsigned short*)(ws + off);                                 // 2.00 MB

  (void)hipFuncSetAttribute((const void*)fused_all_k,
                            hipFuncAttributeMaxDynamicSharedMemorySize, FK_LDS);

  prep_k<<<PREP_BLOCKS, 256, 0, stream>>>(W1, W2, Wq1, bq1, Wq2, bq2, Wh, bh,
                                          w1b, w2c, qoff);

  fused_all_k<<<B_ROWS / 64, 512, FK_LDS, stream>>>(
      state, action, w1b, w2c, b1, g1, be1, b2, g2, be2, Wh, qoff, out);
}

// Round 20
// 102.913 us; speedup vs baseline: 1.4598x; 1.0030x over previous
//
#include <hip/hip_runtime.h>
#include <hip/hip_bf16.h>
#include <cstddef>

// Problem constants
#define B_ROWS 16384
#define SDIM 512
#define ADIM 64
#define KDIM 576    // SDIM + ADIM = 9 K-tiles of 64 (exact)
#define HID 1024
#define NQ 64
#define NT1 9
#define NT2 16

// prep: W1 transpose + coalesced-w2c + qoff, ONE dispatch
#define T1_BLOCKS ((KDIM / 32) * (HID / 32))   // 576
#define W2C_BLOCKS 512                          // 1024 32x32 tiles, 2 per block
#define PREP_BLOCKS (T1_BLOCKS + W2C_BLOCKS + 1)

#define FK_LDS (16384 + 131072)   // A double-buffer (2x8KB) + B1/h1 region (128KB)

typedef __attribute__((ext_vector_type(8))) __bf16 bf16x8;
typedef __attribute__((ext_vector_type(4))) float f32x4;

static __device__ __forceinline__ float bf2f(unsigned short u) {
  union { unsigned int i; float f; } x; x.i = ((unsigned int)u) << 16; return x.f;
}
static __device__ __forceinline__ unsigned short f2bf(float f) {
  union { float f; unsigned int i; } x; x.f = f;
  unsigned int i = x.i + (0x7fffu + ((x.i >> 16) & 1u)); // RNE
  return (unsigned short)(i >> 16);
}

static __device__ __forceinline__ void gload_lds16(const unsigned short* g, unsigned short* l) {
  __builtin_amdgcn_global_load_lds(
      (const __attribute__((address_space(1))) void*)(const void*)g,
      (__attribute__((address_space(3))) void*)(void*)l, 16, 0, 0);
}

// pack 8 f32 -> 8 bf16 (RNE) in one uint4
static __device__ __forceinline__ uint4 pack8(float4 a, float4 b) {
  uint4 o;
  o.x = (unsigned)f2bf(a.x) | ((unsigned)f2bf(a.y) << 16);
  o.y = (unsigned)f2bf(a.z) | ((unsigned)f2bf(a.w) << 16);
  o.z = (unsigned)f2bf(b.x) | ((unsigned)f2bf(b.y) << 16);
  o.w = (unsigned)f2bf(b.z) | ((unsigned)f2bf(b.w) << 16);
  return o;
}

// ---- prep (single dispatch): W1 transpose + coalesced w2c + qoff ----
// w2c mapping (r18-verified): for output neuron r and k-base k (k%8==0):
//   w=r>>7, ni=(r>>4)&7, lan_lo=r&15; t=k>>6, kk=(k>>5)&1, l_hi=(k>>3)&3;
//   chunk=((w*16+t)*2+kk)*8+ni; lane=l_hi*16+lan_lo;
//   w2c[(chunk*64+lane)*8 + j] = bf16(W2[(k+j)*HID + r]), j=0..7.
__global__ __launch_bounds__(256) void prep_k(
    const float* __restrict__ W1, const float* __restrict__ W2,
    const float* __restrict__ Wq1, const float* __restrict__ bq1,
    const float* __restrict__ Wq2, const float* __restrict__ bq2,
    const float* __restrict__ Wh, const float* __restrict__ bh,
    unsigned short* __restrict__ w1b, unsigned short* __restrict__ w2c,
    float* __restrict__ qoff) {
  __shared__ unsigned short tile[2 * 32 * 33];
  const int b = blockIdx.x;
  if (b < T1_BLOCKS) {
    // W1 [KDIM][HID] f32 -> w1b [HID][KDIM] bf16
    const int k0 = (b / 32) * 32, n0 = (b % 32) * 32;
    const int tx = threadIdx.x & 31, ty = threadIdx.x >> 5;
#pragma unroll
    for (int i = 0; i < 32; i += 8)
      tile[(ty + i) * 33 + tx] = f2bf(W1[(size_t)(k0 + ty + i) * HID + n0 + tx]);
    __syncthreads();
#pragma unroll
    for (int i = 0; i < 32; i += 8)
      w1b[(size_t)(n0 + ty + i) * KDIM + k0 + tx] = tile[tx * 33 + ty + i];
  } else if (b < T1_BLOCKS + W2C_BLOCKS) {
    // two 32x32 W2 tiles per block through LDS
    const int tp = (b - T1_BLOCKS) * 2 + ((int)threadIdx.x >> 7);  // tile idx
    const int k0 = (tp & 31) * 32, r0 = (tp >> 5) * 32;
    const int tid2 = (int)threadIdx.x & 127;
    unsigned short* tl = tile + (((int)threadIdx.x >> 7) * 32 * 33);
    {
      const int rx = tid2 & 31, ky = tid2 >> 5;  // ky 0..3
#pragma unroll
      for (int i = 0; i < 8; ++i)
        tl[(ky * 8 + i) * 33 + rx] = f2bf(W2[(size_t)(k0 + ky * 8 + i) * HID + r0 + rx]);
    }
    __syncthreads();
    {
      const int r_off = tid2 & 31, s = tid2 >> 5;  // s 0..3 (k-group)
      const int r = r0 + r_off, k = k0 + s * 8;
      const int wq = r >> 7, ni = (r >> 4) & 7, lan_lo = r & 15;
      const int t = k >> 6, kk = (k >> 5) & 1, l_hi = (k >> 3) & 3;
      const int chunk = ((wq * 16 + t) * 2 + kk) * 8 + ni;
      const int lane = l_hi * 16 + lan_lo;
      uint4 ov;
      unsigned int* op = (unsigned int*)&ov;
#pragma unroll
      for (int i = 0; i < 4; ++i)
        op[i] = (unsigned)tl[(s * 8 + 2 * i) * 33 + r_off]
              | ((unsigned)tl[(s * 8 + 2 * i + 1) * 33 + r_off] << 16);
      *(uint4*)(w2c + (size_t)(chunk * 64 + lane) * 8) = ov;
    }
  } else {
    const int q = threadIdx.x;
    if (q < NQ) {
      const float tau = ((float)q + 0.5f) * (1.0f / (float)NQ);
      float t1[64];
#pragma unroll
      for (int k = 0; k < 64; ++k) t1[k] = fmaxf(fmaf(tau, Wq1[k], bq1[k]), 0.f);
      float acc = bh[0];
#pragma unroll 1
      for (int j = 0; j < 64; ++j) {
        float t2 = bq2[j];
#pragma unroll
        for (int k = 0; k < 64; ++k) t2 = fmaf(t1[k], Wq2[k * 64 + j], t2);
        acc = fmaf(t2, Wh[HID + j], acc);
      }
      qoff[q] = acc;
    }
  }
}

// ============================================================================
// WHOLE-NETWORK single kernel — the r17/r18/r19-measured build (~79 us,
// absmax 7.8e-3). Phase 1: layer-1 GEMM (r13 XSRC skeleton, r15-remapped B1
// frags); epilogue 1 writes LN1+ReLU h1 into LDS (3-bit swizzle); phase 2:
// barrier-free layer-2 GEMM (A from resident LDS, W2 streamed from
// fragment-contiguous w2c); epilogue 2: LN2+ReLU Wf-dot + qoff -> f32 out.
// ============================================================================
__global__ __launch_bounds__(512, 2) void fused_all_k(
    const float* __restrict__ Xs, const float* __restrict__ Xa,
    const unsigned short* __restrict__ B1t,  // w1b [1024][576]
    const unsigned short* __restrict__ w2c,  // frag-contiguous W2 (2MB)
    const float* __restrict__ b1, const float* __restrict__ g1,
    const float* __restrict__ be1,
    const float* __restrict__ b2, const float* __restrict__ g2,
    const float* __restrict__ be2,
    const float* __restrict__ Wh, const float* __restrict__ qoff,
    float* __restrict__ Qout) {
  extern __shared__ unsigned short sm[];
  __shared__ float part[8][64][2];
  __shared__ float murs[64][2];
  __shared__ float dotf[64];
  __shared__ float qof[64];

  const int tid = threadIdx.x;
  const int w = tid >> 6, l = tid & 63;
  const int r0 = (int)blockIdx.x * 64;
  const int sb = (int)blockIdx.x % NT1;     // phase-1 K stagger

  const int sce = ((((l & 7) << 4) ^ (((l >> 3) & 4) << 3)) >> 1);
  const int lr = (l & 15) << 7;
  const int cSw = (((l >> 4) << 4) ^ ((l & 4) << 3));
  // 3-bit swizzled slot bytes for h1-region reads
  const int sl20 = (((l >> 4) ^ (l & 7)) << 4);
  const int sl21 = ((((l >> 4) | 4) ^ (l & 7)) << 4);

  f32x4 acc[4][8] = {};
  float4 ar0, ar1;

#define KT(x) ((((x) + sb) % NT1) << 6)
#define AF1(d, mi, kk) (*(const bf16x8*)(sm + (((d)*8192 + (mi)*2048 + lr + cSw + ((kk) << 6)) >> 1)))
#define BF1(ni, kk) (*(const bf16x8*)(sm + ((16384 + w*16384 + ((l & 15) * 8 + (ni)) * 128 + (((l >> 4) << 4) ^ (((ni) & 4) << 3)) + ((kk) << 6)) >> 1)))
#define ALOADX(kt) do { \
    const int row_ = r0 + w * 8 + (l >> 3); \
    if ((kt) < SDIM) { const float* p_ = Xs + (size_t)row_ * SDIM + (kt) + sce; \
      ar0 = *(const float4*)p_; ar1 = *(const float4*)(p_ + 4); } \
    else { const float* p_ = Xa + (size_t)row_ * ADIM + ((kt) - SDIM) + sce; \
      ar0 = *(const float4*)p_; ar1 = *(const float4*)(p_ + 4); } } while (0)
#define AWRX(d) (*(uint4*)(sm + (((d)*8192 + w * 1024 + l * 16) >> 1)) = pack8(ar0, ar1))
#define ISSUE_B1(kt) do { _Pragma("unroll") for (int i_ = 0; i_ < 16; ++i_) \
    gload_lds16(B1t + (size_t)(w * 128 + i_ * 8 + (l >> 3)) * KDIM + (kt) + sce, \
                sm + ((16384 + w * 16384 + i_ * 1024) >> 1)); } while (0)
#define AF2(t, mi, kk) (*(const bf16x8*)(sm + ((16384 + ((t) >> 1) * 16384 + ((t) & 1) * 8192 + (mi)*2048 + lr + ((kk) ? sl21 : sl20)) >> 1)))
#define LOADB2H(dst, t, kk, h) do { _Pragma("unroll") for (int j_ = 0; j_ < 4; ++j_) \
    dst[j_] = *(const bf16x8*)(w2c + ((size_t)((((w * NT2 + (t)) * 2 + (kk)) * 8 + (h) * 4 + j_) * 64 + l) * 8)); } while (0)
#define MQ1(bsrc) do { _Pragma("unroll") for (int mi = 0; mi < 4; ++mi) \
    _Pragma("unroll") for (int ni = 0; ni < 8; ++ni) \
      acc[mi][ni] = __builtin_amdgcn_mfma_f32_16x16x32_bf16(af[mi], bsrc[ni], acc[mi][ni], 0, 0, 0); } while (0)
#define MQ2(cv, NO) do { _Pragma("unroll") for (int mi = 0; mi < 4; ++mi) \
    _Pragma("unroll") for (int j_ = 0; j_ < 4; ++j_) \
      acc[mi][(NO) + j_] = __builtin_amdgcn_mfma_f32_16x16x32_bf16(af2[mi], cv[j_], acc[mi][(NO) + j_], 0, 0, 0); } while (0)
#define BAR() __builtin_amdgcn_s_barrier()
#define WAITLGKM() asm volatile("s_waitcnt lgkmcnt(0)" ::: "memory")
#define WAITVM(n) asm volatile("s_waitcnt vmcnt(" #n ")" ::: "memory")
#define PRIO1() __builtin_amdgcn_s_setprio(1)
#define PRIO0() __builtin_amdgcn_s_setprio(0)

  // ---------------- phase 1: layer-1 GEMM ----------------
  ALOADX(KT(0)); AWRX(0);
  ISSUE_B1(KT(0));
  ALOADX(KT(1));
  WAITLGKM(); BAR();

  for (int t = 0; t < NT1; ++t) {
    const int d = t & 1;
    if (t + 1 < NT1) { WAITVM(2); } else { WAITVM(0); }
    bf16x8 af[4], bfr[8];
#pragma unroll
    for (int mi = 0; mi < 4; ++mi) af[mi] = AF1(d, mi, 0);
#pragma unroll
    for (int ni = 0; ni < 8; ++ni) bfr[ni] = BF1(ni, 0);
    PRIO1(); MQ1(bfr); PRIO0();
#pragma unroll
    for (int mi = 0; mi < 4; ++mi) af[mi] = AF1(d, mi, 1);
#pragma unroll
    for (int ni = 0; ni < 8; ++ni) bfr[ni] = BF1(ni, 1);
    WAITLGKM();
    if (t + 1 < NT1) ISSUE_B1(KT(t + 1));
    if (t + 1 < NT1) AWRX((t + 1) & 1);
    PRIO1(); MQ1(bfr); PRIO0();
    if (t + 1 < NT1) { WAITLGKM(); }
    BAR();
    if (t + 2 < NT1) ALOADX(KT(t + 2));
  }

  // ---------------- epilogue 1: LN1+ReLU -> h1 into LDS ----------------
  float bcol[8], gcol[8], becol[8];
  const int cb = w * 128 + (l & 15) * 8;
  *(float4*)&bcol[0]  = *(const float4*)(b1 + cb);
  *(float4*)&bcol[4]  = *(const float4*)(b1 + cb + 4);
  *(float4*)&gcol[0]  = *(const float4*)(g1 + cb);
  *(float4*)&gcol[4]  = *(const float4*)(g1 + cb + 4);
  *(float4*)&becol[0] = *(const float4*)(be1 + cb);
  *(float4*)&becol[4] = *(const float4*)(be1 + cb + 4);
#pragma unroll
  for (int mi = 0; mi < 4; ++mi)
#pragma unroll
    for (int rr = 0; rr < 4; ++rr) {
      float s1 = 0.f, s2 = 0.f;
#pragma unroll
      for (int ni = 0; ni < 8; ++ni) {
        const float x = acc[mi][ni][rr] + bcol[ni];
        s1 += x; s2 += x * x;
      }
#pragma unroll
      for (int o = 1; o < 16; o <<= 1) {
        s1 += __shfl_xor(s1, o, 64);
        s2 += __shfl_xor(s2, o, 64);
      }
      if ((l & 15) == 0) {
        const int row = mi * 16 + (l >> 4) * 4 + rr;
        part[w][row][0] = s1;
        part[w][row][1] = s2;
      }
    }
  __syncthreads();
  if (tid < 64) {
    float s1 = 0.f, s2 = 0.f;
#pragma unroll
    for (int ww = 0; ww < 8; ++ww) { s1 += part[ww][tid][0]; s2 += part[ww][tid][1]; }
    const float mu = s1 * (1.0f / HID);
    murs[tid][0] = mu;
    murs[tid][1] = rsqrtf(s2 * (1.0f / HID) - mu * mu + 1e-5f);
    qof[tid] = qoff[tid];
  }
  __syncthreads();
#pragma unroll
  for (int mi = 0; mi < 4; ++mi)
#pragma unroll
    for (int rr = 0; rr < 4; ++rr) {
      const int row = mi * 16 + (l >> 4) * 4 + rr;
      const float mu = murs[row][0], rs = murs[row][1];
      uint4 ov;
      unsigned int* op = (unsigned int*)&ov;
#pragma unroll
      for (int i = 0; i < 4; ++i) {
        const float y0 = fmaxf((acc[mi][2 * i][rr] + bcol[2 * i] - mu) * rs * gcol[2 * i] + becol[2 * i], 0.f);
        const float y1 = fmaxf((acc[mi][2 * i + 1][rr] + bcol[2 * i + 1] - mu) * rs * gcol[2 * i + 1] + becol[2 * i + 1], 0.f);
        op[i] = (unsigned)f2bf(y0) | ((unsigned)f2bf(y1) << 16);
      }
      *(uint4*)(sm + ((16384 + w * 16384 + ((l & 15) >> 3) * 8192 + row * 128
                       + (((l & 7) ^ (row & 7)) << 4)) >> 1)) = ov;
    }
  __syncthreads();

  // ---------------- phase 2: layer-2 GEMM, barrier-free ----------------
#pragma unroll
  for (int mi = 0; mi < 4; ++mi)
#pragma unroll
    for (int ni = 0; ni < 8; ++ni) acc[mi][ni] = (f32x4){0.f, 0.f, 0.f, 0.f};

  {
    bf16x8 ca[4], cbf[4], af2[4];
    LOADB2H(ca, 0, 0, 0);
    for (int t = 0; t < NT2; ++t) {
#pragma unroll
      for (int mi = 0; mi < 4; ++mi) af2[mi] = AF2(t, mi, 0);
      LOADB2H(cbf, t, 0, 1);
      PRIO1(); MQ2(ca, 0); PRIO0();
      LOADB2H(ca, t, 1, 0);
      PRIO1(); MQ2(cbf, 4); PRIO0();
#pragma unroll
      for (int mi = 0; mi < 4; ++mi) af2[mi] = AF2(t, mi, 1);
      LOADB2H(cbf, t, 1, 1);
      PRIO1(); MQ2(ca, 0); PRIO0();
      if (t + 1 < NT2) LOADB2H(ca, t + 1, 0, 0);
      PRIO1(); MQ2(cbf, 4); PRIO0();
    }
  }

  // ---------------- epilogue 2: LN2+ReLU + Wf-dot + qoff ----------------
  float b2c[8], g2c[8], be2c[8], wf[8];
#pragma unroll
  for (int ni = 0; ni < 8; ++ni) {
    const int col = w * 128 + ni * 16 + (l & 15);
    b2c[ni] = b2[col];
    g2c[ni] = g2[col];
    be2c[ni] = be2[col];
    wf[ni] = Wh[col];
  }
#pragma unroll
  for (int mi = 0; mi < 4; ++mi)
#pragma unroll
    for (int rr = 0; rr < 4; ++rr) {
      float s1 = 0.f, s2 = 0.f;
#pragma unroll
      for (int ni = 0; ni < 8; ++ni) {
        const float x = acc[mi][ni][rr] + b2c[ni];
        s1 += x; s2 += x * x;
      }
#pragma unroll
      for (int o = 1; o < 16; o <<= 1) {
        s1 += __shfl_xor(s1, o, 64);
        s2 += __shfl_xor(s2, o, 64);
      }
      if ((l & 15) == 0) {
        const int row = mi * 16 + (l >> 4) * 4 + rr;
        part[w][row][0] = s1;
        part[w][row][1] = s2;
      }
    }
  __syncthreads();
  if (tid < 64) {
    float s1 = 0.f, s2 = 0.f;
#pragma unroll
    for (int ww = 0; ww < 8; ++ww) { s1 += part[ww][tid][0]; s2 += part[ww][tid][1]; }
    const float mu = s1 * (1.0f / HID);
    murs[tid][0] = mu;
    murs[tid][1] = rsqrtf(s2 * (1.0f / HID) - mu * mu + 1e-5f);
  }
  __syncthreads();
#pragma unroll
  for (int mi = 0; mi < 4; ++mi)
#pragma unroll
    for (int rr = 0; rr < 4; ++rr) {
      const int row = mi * 16 + (l >> 4) * 4 + rr;
      const float mu = murs[row][0], rs = murs[row][1];
      float dp = 0.f;
#pragma unroll
      for (int ni = 0; ni < 8; ++ni) {
        const float x = acc[mi][ni][rr] + b2c[ni];
        dp += fmaxf((x - mu) * rs * g2c[ni] + be2c[ni], 0.f) * wf[ni];
      }
#pragma unroll
      for (int o = 1; o < 16; o <<= 1) dp += __shfl_xor(dp, o, 64);
      if ((l & 15) == 0) part[w][row][0] = dp;
    }
  __syncthreads();
  if (tid < 64) {
    float dsum = 0.f;
#pragma unroll
    for (int ww = 0; ww < 8; ++ww) dsum += part[ww][tid][0];
    dotf[tid] = dsum;
  }
  __syncthreads();
#pragma unroll
  for (int it = 0; it < 8; ++it) {
    const int idx = tid + it * 512;
    const int row = idx >> 6, q = idx & 63;
    Qout[(size_t)(r0 + row) * NQ + q] = dotf[row] + qof[q];
  }
#undef KT
#undef AF1
#undef BF1
#undef ALOADX
#undef AWRX
#undef ISSUE_B1
#undef AF2
#undef LOADB2H
#undef MQ1
#undef MQ2
#undef BAR
#undef WAITLGKM
#undef WAITVM
}

extern "C" void kernel_launch(void* const* d_in, const int* in_sizes, int n_in,
                              void* d_out, int out_size, void* d_ws, size_t ws_size,
                              hipStream_t stream) {
  const float* state  = (const float*)d_in[0];
  const float* action = (const float*)d_in[1];
  const float* W1  = (const float*)d_in[2];
  const float* b1  = (const float*)d_in[3];
  const float* g1  = (const float*)d_in[4];
  const float* be1 = (const float*)d_in[5];
  const float* W2  = (const float*)d_in[6];
  const float* b2  = (const float*)d_in[7];
  const float* g2  = (const float*)d_in[8];
  const float* be2 = (const float*)d_in[9];
  const float* Wq1 = (const float*)d_in[10];
  const float* bq1 = (const float*)d_in[11];
  const float* Wq2 = (const float*)d_in[12];
  const float* bq2 = (const float*)d_in[13];
  const float* Wh  = (const float*)d_in[14];
  const float* bh  = (const float*)d_in[15];
  float* out = (float*)d_out;

  // workspace (~3.2 MB)
  char* ws = (char*)d_ws;
  size_t off = 0;
  float* qoff = (float*)(ws + off); off += 256;
  unsigned short* w1b = (unsigned short*)(ws + off); off += (size_t)HID * KDIM * 2;  // 1.18 MB
  unsigned short* w2c = (unsigned short*)(ws + off);                                 // 2.00 MB

  (void)hipFuncSetAttribute((const void*)fused_all_k,
                            hipFuncAttributeMaxDynamicSharedMemorySize, FK_LDS);

  prep_k<<<PREP_BLOCKS, 256, 0, stream>>>(W1, W2, Wq1, bq1, Wq2, bq2, Wh, bh,
                                          w1b, w2c, qoff);

  fused_all_k<<<B_ROWS / 64, 512, FK_LDS, stream>>>(
      state, action, w1b, w2c, b1, g1, be1, b2, g2, be2, Wh, qoff, out);
}